// Round 15
// baseline (602.003 us; speedup 1.0000x reference)
//
#include <hip/hip_runtime.h>

// ---------------------------------------------------------------------------
// SFGCN forward on MI355X, round 15:
//  - Counting-sort geometry retune: 512-row buckets (391 total, was 782x256)
//    -> 2x longer contiguous runs per (block,bucket) in coarse_scatter;
//    NBLK1 1024 (was 512) -> 4 blocks/CU, 2x latency hiding.
//  - hw INTERLEAVED [n][128] (S=feats 0-63, C=64-127): spmm_dual64 gathers
//    ONE 256B row per edge (was 2x128B from two arrays).
//  - MFMA dense chain, reduce-scatter final_fuse, bf16 gathers unchanged.
// ---------------------------------------------------------------------------

typedef unsigned short ushort_t;
typedef float f32x4 __attribute__((ext_vector_type(4)));
typedef short short8 __attribute__((ext_vector_type(8)));

#define NBLK1 1024      // blocks for coarse hist/scatter (grid-stride)
#define BKT_BITS 9      // 512 rows per coarse bucket
#define BKT_ROWS 512

__device__ __forceinline__ ushort_t f2bf(float f) {  // round-to-nearest-even
  unsigned u = __float_as_uint(f);
  unsigned r = (u + 0x7FFFu + ((u >> 16) & 1u)) >> 16;
  return (ushort_t)r;
}
__device__ __forceinline__ float bf2f(ushort_t b) {
  return __uint_as_float((unsigned)b << 16);
}

// reduce-scatter 16 values across a 16-lane group: lane ends with the full
// 16-lane sum of element [lane&15]. 15 shfl, compile-time register indices.
__device__ __forceinline__ float rs16(const float a[16], int lane) {
  bool b8 = (lane & 8) != 0;
  float t[8];
#pragma unroll
  for (int j = 0; j < 8; ++j) {
    float sent = b8 ? a[j] : a[j + 8];
    float mine = b8 ? a[j + 8] : a[j];
    t[j] = mine + __shfl_xor(sent, 8);
  }
  bool b4 = (lane & 4) != 0;
  float u[4];
#pragma unroll
  for (int j = 0; j < 4; ++j) {
    float sent = b4 ? t[j] : t[j + 4];
    float mine = b4 ? t[j + 4] : t[j];
    u[j] = mine + __shfl_xor(sent, 4);
  }
  bool b2 = (lane & 2) != 0;
  float v[2];
#pragma unroll
  for (int j = 0; j < 2; ++j) {
    float s2 = b2 ? u[j] : u[j + 2];
    float m2 = b2 ? u[j + 2] : u[j];
    v[j] = m2 + __shfl_xor(s2, 2);
  }
  bool b1 = (lane & 1) != 0;
  float s1 = b1 ? v[0] : v[1];
  float m1 = b1 ? v[1] : v[0];
  return m1 + __shfl_xor(s1, 1);
}

// total4 float4 chunks -> ushort4 bf16 chunks
__global__ __launch_bounds__(256) void cvt_bf16(
    const float* __restrict__ in, ushort_t* __restrict__ out, long total4) {
  long i = (long)blockIdx.x * 256 + threadIdx.x;
  if (i >= total4) return;
  float4 v = ((const float4*)in)[i];
  ushort4 o;
  o.x = f2bf(v.x);
  o.y = f2bf(v.y);
  o.z = f2bf(v.z);
  o.w = f2bf(v.w);
  ((ushort4*)out)[i] = o;
}

// Transpose+cast the 3 weight pairs to bf16.
__global__ __launch_bounds__(256) void prep_weights(
    const float* __restrict__ w1a, const float* __restrict__ w1b,
    const float* __restrict__ w1c, const float* __restrict__ w2a,
    const float* __restrict__ w2b, const float* __restrict__ w2c,
    ushort_t* __restrict__ o1a, ushort_t* __restrict__ o1b,
    ushort_t* __restrict__ o1c, ushort_t* __restrict__ o2a,
    ushort_t* __restrict__ o2b, ushort_t* __restrict__ o2c) {
  int i = blockIdx.x * 256 + threadIdx.x;
  if (i < 49152) {  // 3 x 128x128
    int a = i >> 14, j = i & 16383;
    int nn = j >> 7, k = j & 127;
    const float* s = (a == 0) ? w1a : (a == 1) ? w1b : w1c;
    ushort_t* d = (a == 0) ? o1a : (a == 1) ? o1b : o1c;
    d[j] = f2bf(s[k * 128 + nn]);
  } else if (i < 73728) {  // 3 x 64x128
    int i2 = i - 49152;
    int a = i2 >> 13, j = i2 & 8191;
    int h = j >> 7, k = j & 127;
    const float* s = (a == 0) ? w2a : (a == 1) ? w2b : w2c;
    ushort_t* d = (a == 0) ? o2a : (a == 1) ? o2b : o2c;
    d[j] = f2bf(s[k * 64 + h]);
  }
}

// ---------------- two-level counting sort CSR build ----------------
// vrow in [0, 2n); bucket = vrow >> BKT_BITS (391 buckets of 512 rows).

__global__ __launch_bounds__(256) void coarse_hist(
    const int* __restrict__ rowS, const int* __restrict__ rowF,
    int* __restrict__ bkt_cnt, int n, int e, int nb) {
  __shared__ int lh[400];
  int t = threadIdx.x;
  for (int j = t; j < nb; j += 256) lh[j] = 0;
  __syncthreads();
  long total = 2L * e;
  long stride = (long)NBLK1 * 256;
  for (long i = (long)blockIdx.x * 256 + t; i < total; i += stride) {
    int vrow = (i < e) ? rowS[i] : (n + rowF[i - e]);
    atomicAdd(&lh[vrow >> BKT_BITS], 1);
  }
  __syncthreads();
  for (int j = t; j < nb; j += 256)
    if (lh[j]) atomicAdd(&bkt_cnt[j], lh[j]);
}

__global__ __launch_bounds__(256) void coarse_scan(
    const int* __restrict__ cnt, int* __restrict__ off, int nb, int total) {
  __shared__ int lds[256];
  int t = threadIdx.x;
  int c[4];
  int s = 0;
#pragma unroll
  for (int j = 0; j < 4; ++j) {
    int idx = t * 4 + j;
    c[j] = (idx < nb) ? cnt[idx] : 0;
    s += c[j];
  }
  lds[t] = s;
  __syncthreads();
#pragma unroll
  for (int d = 1; d < 256; d <<= 1) {
    int v = (t >= d) ? lds[t - d] : 0;
    __syncthreads();
    lds[t] += v;
    __syncthreads();
  }
  int o = (t == 0) ? 0 : lds[t - 1];
#pragma unroll
  for (int j = 0; j < 4; ++j) {
    int idx = t * 4 + j;
    if (idx < nb) off[idx] = o;
    o += c[j];
  }
  if (t == 0) off[nb] = total;
}

// tmp[p] = (col | vlow<<20, val_bits); col < 2^20, vlow = vrow & 511.
__global__ __launch_bounds__(256) void coarse_scatter(
    const int* __restrict__ rowS, const int* __restrict__ colS,
    const float* __restrict__ valS, const int* __restrict__ rowF,
    const int* __restrict__ colF, const float* __restrict__ valF,
    const int* __restrict__ bkt_off, int* __restrict__ bkt_woff,
    int2* __restrict__ tmp, int n, int e, int nb) {
  __shared__ int lh[400];
  __shared__ int lb[400];
  __shared__ int gb[400];
  int t = threadIdx.x;
  for (int j = t; j < nb; j += 256) {
    lh[j] = 0;
    lb[j] = 0;
  }
  __syncthreads();
  long total = 2L * e;
  long stride = (long)NBLK1 * 256;
  for (long i = (long)blockIdx.x * 256 + t; i < total; i += stride) {
    int vrow = (i < e) ? rowS[i] : (n + rowF[i - e]);
    atomicAdd(&lh[vrow >> BKT_BITS], 1);
  }
  __syncthreads();
  for (int j = t; j < nb; j += 256) {
    int h = lh[j];
    gb[j] = h ? (bkt_off[j] + atomicAdd(&bkt_woff[j], h)) : 0;
  }
  __syncthreads();
  for (long i = (long)blockIdx.x * 256 + t; i < total; i += stride) {
    int vrow, c;
    float v;
    if (i < e) {
      vrow = rowS[i];
      c = colS[i];
      v = valS[i];
    } else {
      vrow = n + rowF[i - e];
      c = colF[i - e];
      v = valF[i - e];
    }
    int b = vrow >> BKT_BITS;
    int k = atomicAdd(&lb[b], 1);
    tmp[gb[b] + k] =
        make_int2(c | ((vrow & (BKT_ROWS - 1)) << 20), __float_as_int(v));
  }
}

// one block per 512-row bucket: LDS hist + scan -> rowptr, then scatter
// within the bucket's ~64KB window (L2-resident).
__global__ __launch_bounds__(256) void fine_sort(
    const int* __restrict__ bkt_off, const int2* __restrict__ tmp,
    int2* __restrict__ packed, int* __restrict__ rowptr, int vtotal,
    int etotal) {
  __shared__ int hist[512];
  __shared__ int scn[256];
  __shared__ int rowb[512];
  __shared__ int bump[512];
  int b = blockIdx.x;
  int t = threadIdx.x;
  int lo = bkt_off[b], hi = bkt_off[b + 1];
  hist[t] = 0;
  hist[t + 256] = 0;
  bump[t] = 0;
  bump[t + 256] = 0;
  __syncthreads();
  for (int i = lo + t; i < hi; i += 256)
    atomicAdd(&hist[((unsigned)tmp[i].x) >> 20], 1);
  __syncthreads();
  int s = hist[2 * t] + hist[2 * t + 1];
  scn[t] = s;
  __syncthreads();
#pragma unroll
  for (int d = 1; d < 256; d <<= 1) {
    int v = (t >= d) ? scn[t - d] : 0;
    __syncthreads();
    scn[t] += v;
    __syncthreads();
  }
  int pre = (t == 0) ? 0 : scn[t - 1];
  int r0 = lo + pre;
  int r1 = r0 + hist[2 * t];
  rowb[2 * t] = r0;
  rowb[2 * t + 1] = r1;
  int vrow0 = b * BKT_ROWS + 2 * t;
  if (vrow0 < vtotal) rowptr[vrow0] = r0;
  if (vrow0 + 1 < vtotal) rowptr[vrow0 + 1] = r1;
  __syncthreads();
  for (int i = lo + t; i < hi; i += 256) {
    int2 p = tmp[i];
    int vl = ((unsigned)p.x) >> 20;
    int dest = rowb[vl] + atomicAdd(&bump[vl], 1);
    packed[dest] = make_int2(p.x & 0xFFFFF, p.y);
  }
  if (b == 0 && t == 0) rowptr[vtotal] = etotal;
}

// ---------------- CSR SpMM (bf16 gather, fp32 accumulate) ----------------

__global__ __launch_bounds__(256) void spmm_csr_128(
    const int* __restrict__ rowptr, const int2* __restrict__ packed,
    const ushort_t* __restrict__ h, ushort_t* __restrict__ Ax, int n) {
  int tid = threadIdx.x;
  int r = blockIdx.x * 8 + (tid >> 5);
  if (r >= n) return;
  int lane = tid & 31;
  int lo = rowptr[r], hi = rowptr[r + 1];
  const ushort4* h4 = (const ushort4*)h;  // row stride = 32 ushort4
  float4 acc = make_float4(0.f, 0.f, 0.f, 0.f);
  int e = lo;
  for (; e + 4 <= hi; e += 4) {
    int2 p0 = packed[e], p1 = packed[e + 1], p2 = packed[e + 2],
         p3 = packed[e + 3];
    float v0 = __int_as_float(p0.y), v1 = __int_as_float(p1.y),
          v2 = __int_as_float(p2.y), v3 = __int_as_float(p3.y);
    ushort4 q0 = h4[(long)p0.x * 32 + lane];
    ushort4 q1 = h4[(long)p1.x * 32 + lane];
    ushort4 q2 = h4[(long)p2.x * 32 + lane];
    ushort4 q3 = h4[(long)p3.x * 32 + lane];
    acc.x += v0 * bf2f(q0.x) + v1 * bf2f(q1.x) + v2 * bf2f(q2.x) + v3 * bf2f(q3.x);
    acc.y += v0 * bf2f(q0.y) + v1 * bf2f(q1.y) + v2 * bf2f(q2.y) + v3 * bf2f(q3.y);
    acc.z += v0 * bf2f(q0.z) + v1 * bf2f(q1.z) + v2 * bf2f(q2.z) + v3 * bf2f(q3.z);
    acc.w += v0 * bf2f(q0.w) + v1 * bf2f(q1.w) + v2 * bf2f(q2.w) + v3 * bf2f(q3.w);
  }
  for (; e < hi; ++e) {
    int2 p = packed[e];
    float v = __int_as_float(p.y);
    ushort4 q = h4[(long)p.x * 32 + lane];
    acc.x += v * bf2f(q.x);
    acc.y += v * bf2f(q.y);
    acc.z += v * bf2f(q.z);
    acc.w += v * bf2f(q.w);
  }
  ushort4 o;
  o.x = f2bf(acc.x);
  o.y = f2bf(acc.y);
  o.z = f2bf(acc.z);
  o.w = f2bf(acc.w);
  ((ushort4*)Ax)[(long)r * 32 + lane] = o;
}

// Dual 64-feat SpMM over INTERLEAVED hI[n][128] (S=0..63, C=64..127):
// one 256B contiguous row gather per edge; lanes 0-15 -> S, 16-31 -> C.
__global__ __launch_bounds__(256) void spmm_dual64(
    const int* __restrict__ rowptr, const int2* __restrict__ packed,
    const ushort_t* __restrict__ hI, const float* __restrict__ bS,
    const float* __restrict__ bC, float* __restrict__ outS,
    float* __restrict__ outC, int n) {
  int tid = threadIdx.x;
  int r = blockIdx.x * 8 + (tid >> 5);
  if (r >= n) return;
  int lane = tid & 31;
  int half = lane >> 4;
  int li = lane & 15;
  const ushort4* h4 = (const ushort4*)hI;  // row = 32 ushort4 (S|C)
  float4 acc = ((const float4*)(half ? bC : bS))[li];
  int lo = rowptr[r], hi = rowptr[r + 1];
  int e = lo;
  for (; e + 4 <= hi; e += 4) {
    int2 p0 = packed[e], p1 = packed[e + 1], p2 = packed[e + 2],
         p3 = packed[e + 3];
    float v0 = __int_as_float(p0.y), v1 = __int_as_float(p1.y),
          v2 = __int_as_float(p2.y), v3 = __int_as_float(p3.y);
    ushort4 q0 = h4[(long)p0.x * 32 + lane];
    ushort4 q1 = h4[(long)p1.x * 32 + lane];
    ushort4 q2 = h4[(long)p2.x * 32 + lane];
    ushort4 q3 = h4[(long)p3.x * 32 + lane];
    acc.x += v0 * bf2f(q0.x) + v1 * bf2f(q1.x) + v2 * bf2f(q2.x) + v3 * bf2f(q3.x);
    acc.y += v0 * bf2f(q0.y) + v1 * bf2f(q1.y) + v2 * bf2f(q2.y) + v3 * bf2f(q3.y);
    acc.z += v0 * bf2f(q0.z) + v1 * bf2f(q1.z) + v2 * bf2f(q2.z) + v3 * bf2f(q3.z);
    acc.w += v0 * bf2f(q0.w) + v1 * bf2f(q1.w) + v2 * bf2f(q2.w) + v3 * bf2f(q3.w);
  }
  for (; e < hi; ++e) {
    int2 p = packed[e];
    float v = __int_as_float(p.y);
    ushort4 q = h4[(long)p.x * 32 + lane];
    acc.x += v * bf2f(q.x);
    acc.y += v * bf2f(q.y);
    acc.z += v * bf2f(q.z);
    acc.w += v * bf2f(q.w);
  }
  float4* o = (float4*)(half ? outC : outS);
  o[(long)r * 16 + li] = acc;
}

// ---------------- fused dense chain, bf16 MFMA, dual weight sets ----------
// Writes into interleaved HI[n][128] at feature offset hoff (0 or 64).
__device__ __forceinline__ void l1l2_chain(
    const ushort_t* __restrict__ Ax, const ushort_t* __restrict__ W1T,
    const float* __restrict__ B1, const ushort_t* __restrict__ W2T,
    ushort_t* __restrict__ HI, int hoff, int n, long node0, int w, int lo16,
    int g, ushort_t (*sp)[136]) {
  // ---- GEMM1 (flipped): S^T = W1T x Ax^T ----
  f32x4 acc1[2][4];
#pragma unroll
  for (int m = 0; m < 2; ++m)
#pragma unroll
    for (int nu = 0; nu < 4; ++nu) acc1[m][nu] = (f32x4){0.f, 0.f, 0.f, 0.f};

#pragma unroll 1
  for (int t = 0; t < 4; ++t) {
    short8 af0 = *(const short8*)(W1T + (32 * w + lo16) * 128 + 32 * t + 8 * g);
    short8 af1 =
        *(const short8*)(W1T + (32 * w + 16 + lo16) * 128 + 32 * t + 8 * g);
#pragma unroll
    for (int nu = 0; nu < 4; ++nu) {
      long node = node0 + 16 * nu + lo16;
      if (node > (long)n - 1) node = (long)n - 1;
      short8 bf = *(const short8*)(Ax + node * 128 + 32 * t + 8 * g);
      acc1[0][nu] =
          __builtin_amdgcn_mfma_f32_16x16x32_bf16(af0, bf, acc1[0][nu], 0, 0, 0);
      acc1[1][nu] =
          __builtin_amdgcn_mfma_f32_16x16x32_bf16(af1, bf, acc1[1][nu], 0, 0, 0);
    }
  }

  // relu + bias, pack 4 contiguous sfeats -> S' LDS
#pragma unroll
  for (int m = 0; m < 2; ++m) {
    int sf = 32 * w + 16 * m + 4 * g;
    float4 b1v = *(const float4*)(B1 + sf);
#pragma unroll
    for (int nu = 0; nu < 4; ++nu) {
      int node_l = 16 * nu + lo16;
      ushort4 pk;
      pk.x = f2bf(fmaxf(acc1[m][nu][0] + b1v.x, 0.f));
      pk.y = f2bf(fmaxf(acc1[m][nu][1] + b1v.y, 0.f));
      pk.z = f2bf(fmaxf(acc1[m][nu][2] + b1v.z, 0.f));
      pk.w = f2bf(fmaxf(acc1[m][nu][3] + b1v.w, 0.f));
      *(ushort4*)(&sp[node_l][sf]) = pk;
    }
  }
  __syncthreads();

  // ---- GEMM2 (standard): H = S' @ W2 ----
  f32x4 acc2[4];
#pragma unroll
  for (int nu = 0; nu < 4; ++nu) acc2[nu] = (f32x4){0.f, 0.f, 0.f, 0.f};
#pragma unroll 1
  for (int t = 0; t < 4; ++t) {
    short8 af = *(const short8*)(&sp[16 * w + lo16][32 * t + 8 * g]);
#pragma unroll
    for (int nu = 0; nu < 4; ++nu) {
      short8 bf =
          *(const short8*)(W2T + (16 * nu + lo16) * 128 + 32 * t + 8 * g);
      acc2[nu] =
          __builtin_amdgcn_mfma_f32_16x16x32_bf16(af, bf, acc2[nu], 0, 0, 0);
    }
  }
#pragma unroll
  for (int nu = 0; nu < 4; ++nu) {
#pragma unroll
    for (int r = 0; r < 4; ++r) {
      long node = node0 + 16 * w + 4 * g + r;
      if (node < n) HI[node * 128 + hoff + 16 * nu + lo16] = f2bf(acc2[nu][r]);
    }
  }
}

__global__ __launch_bounds__(256) void fused_l1l2_mfma_dual(
    const ushort_t* __restrict__ Ax, const ushort_t* __restrict__ W1Ta,
    const float* __restrict__ B1a, const ushort_t* __restrict__ W2Ta,
    const ushort_t* __restrict__ W1Tb, const float* __restrict__ B1b,
    const ushort_t* __restrict__ W2Tb, ushort_t* __restrict__ HI, int n) {
  __shared__ __attribute__((aligned(16))) ushort_t sp[64][136];
  int tid = threadIdx.x;
  int w = tid >> 6;
  int l = tid & 63;
  int lo16 = l & 15;
  int g = l >> 4;
  long node0 = (long)blockIdx.x * 64;

  l1l2_chain(Ax, W1Ta, B1a, W2Ta, HI, 0, n, node0, w, lo16, g, sp);
  __syncthreads();  // WAR on sp before chain B overwrites
  l1l2_chain(Ax, W1Tb, B1b, W2Tb, HI, 64, n, node0, w, lo16, g, sp);
}

// ---------------- final fuse v3 (reduce-scatter; 16 lanes per node) -------
__global__ __launch_bounds__(256) void final_fuse(
    const float* __restrict__ emb1, const float* __restrict__ emb2,
    const float* __restrict__ com1, const float* __restrict__ com2,
    const float* __restrict__ attw1, const float* __restrict__ attb1,
    const float* __restrict__ attw2, const float* __restrict__ mlpw,
    const float* __restrict__ mlpb, float* __restrict__ out_logp,
    float* __restrict__ out_beta, float* __restrict__ out_emb, int n) {
  __shared__ __attribute__((aligned(16))) float w1t[16][64];
  __shared__ __attribute__((aligned(16))) float mwt[8][64];
  __shared__ float b1s[16];
  __shared__ float w2s[16];
  __shared__ float mbs[8];
  int tid = threadIdx.x;
  for (int idx = tid; idx < 1024; idx += 256)
    w1t[idx & 15][idx >> 4] = attw1[idx];
  for (int idx = tid; idx < 512; idx += 256)
    mwt[idx & 7][idx >> 3] = mlpw[idx];
  if (tid < 16) {
    b1s[tid] = attb1[tid];
    w2s[tid] = attw2[tid];
  }
  if (tid < 8) mbs[tid] = mlpb[tid];
  __syncthreads();

  int lane = tid & 15;
  long i = ((long)blockIdx.x * 256 + tid) >> 4;
  bool alive = i < n;
  long ii = alive ? i : (long)(n - 1);

  float4 z0 = ((const float4*)emb1)[ii * 16 + lane];
  float4 z1 = ((const float4*)emb2)[ii * 16 + lane];
  float4 x1 = ((const float4*)com1)[ii * 16 + lane];
  float4 x2 = ((const float4*)com2)[ii * 16 + lane];
  float4 z2 = make_float4(0.5f * (x1.x + x2.x), 0.5f * (x1.y + x2.y),
                          0.5f * (x1.z + x2.z), 0.5f * (x1.w + x2.w));

  // attention partials
  float a0[16], a1[16], a2[16];
#pragma unroll
  for (int m = 0; m < 16; ++m) {
    float4 w = *(const float4*)&w1t[m][lane * 4];
    a0[m] = z0.x * w.x + z0.y * w.y + z0.z * w.z + z0.w * w.w;
    a1[m] = z1.x * w.x + z1.y * w.y + z1.z * w.z + z1.w * w.w;
    a2[m] = z2.x * w.x + z2.y * w.y + z2.z * w.z + z2.w * w.w;
  }
  // reduce-scatter: lane owns unit m = lane
  float A0 = rs16(a0, lane);
  float A1 = rs16(a1, lane);
  float A2 = rs16(a2, lane);
  // per-lane tanh (3 instead of 48), then all-reduce of the 3 scores
  float bm = b1s[lane], wm = w2s[lane];
  float p0 = tanhf(A0 + bm) * wm;
  float p1 = tanhf(A1 + bm) * wm;
  float p2 = tanhf(A2 + bm) * wm;
#pragma unroll
  for (int d = 1; d < 16; d <<= 1) {
    p0 += __shfl_xor(p0, d);
    p1 += __shfl_xor(p1, d);
    p2 += __shfl_xor(p2, d);
  }
  float mx = fmaxf(p0, fmaxf(p1, p2));
  float ex0 = expf(p0 - mx), ex1 = expf(p1 - mx), ex2 = expf(p2 - mx);
  float inv = 1.f / (ex0 + ex1 + ex2);
  float be0 = ex0 * inv, be1 = ex1 * inv, be2 = ex2 * inv;

  float4 em;
  em.x = be0 * z0.x + be1 * z1.x + be2 * z2.x;
  em.y = be0 * z0.y + be1 * z1.y + be2 * z2.y;
  em.z = be0 * z0.z + be1 * z1.z + be2 * z2.z;
  em.w = be0 * z0.w + be1 * z1.w + be2 * z2.w;
  if (alive) ((float4*)out_emb)[i * 16 + lane] = em;

  // logits partials
  float lg[8];
#pragma unroll
  for (int p = 0; p < 8; ++p) {
    float4 w = *(const float4*)&mwt[p][lane * 4];
    lg[p] = em.x * w.x + em.y * w.y + em.z * w.z + em.w * w.w;
  }
  // reduce-scatter 8 elements over 16 lanes; owner index = 4*b8 + 2*b4 + b2,
  // then the bit-0 pair exchange completes the 16-lane sum.
  bool b8 = (lane & 8) != 0;
  float t4[4];
#pragma unroll
  for (int j = 0; j < 4; ++j) {
    float sent = b8 ? lg[j] : lg[j + 4];
    float mine = b8 ? lg[j + 4] : lg[j];
    t4[j] = mine + __shfl_xor(sent, 8);
  }
  bool b4 = (lane & 4) != 0;
  float t2[2];
#pragma unroll
  for (int j = 0; j < 2; ++j) {
    float sent = b4 ? t4[j] : t4[j + 2];
    float mine = b4 ? t4[j + 2] : t4[j];
    t2[j] = mine + __shfl_xor(sent, 4);
  }
  bool b2 = (lane & 2) != 0;
  {
    float sent = b2 ? t2[0] : t2[1];
    float mine = b2 ? t2[1] : t2[0];
    t2[0] = mine + __shfl_xor(sent, 2);
  }
  t2[0] += __shfl_xor(t2[0], 1);  // lanes l, l^1 hold complementary halves
  int myidx = (b8 ? 4 : 0) + (b4 ? 2 : 0) + (b2 ? 1 : 0);
  float lgv = t2[0] + mbs[myidx];
  // all-reduce max & sum over the 8 distinct indices (d = 2,4,8)
  float m2 = lgv;
  m2 = fmaxf(m2, __shfl_xor(m2, 2));
  m2 = fmaxf(m2, __shfl_xor(m2, 4));
  m2 = fmaxf(m2, __shfl_xor(m2, 8));
  float ev = expf(lgv - m2);
  float ssum = ev;
  ssum += __shfl_xor(ssum, 2);
  ssum += __shfl_xor(ssum, 4);
  ssum += __shfl_xor(ssum, 8);
  float ls = m2 + logf(ssum);

  if (alive) {
    if ((lane & 1) == 0) out_logp[i * 8 + myidx] = lgv - ls;
    if (lane == 0) {
      out_beta[i * 3 + 0] = be0;
      out_beta[i * 3 + 1] = be1;
      out_beta[i * 3 + 2] = be2;
    }
  }
}

extern "C" void kernel_launch(void* const* d_in, const int* in_sizes, int n_in,
                              void* d_out, int out_size, void* d_ws,
                              size_t ws_size, hipStream_t stream) {
  const float* x = (const float*)d_in[0];
  const int* srow = (const int*)d_in[1];
  const int* scol_in = (const int*)d_in[2];
  const float* sval_in = (const float*)d_in[3];
  const int* frow = (const int*)d_in[4];
  const int* fcol_in = (const int*)d_in[5];
  const float* fval_in = (const float*)d_in[6];
  const float* w_s1_1 = (const float*)d_in[7];
  const float* b_s1_1 = (const float*)d_in[8];
  const float* w_s1_2 = (const float*)d_in[9];
  const float* b_s1_2 = (const float*)d_in[10];
  const float* w_s2_1 = (const float*)d_in[11];
  const float* b_s2_1 = (const float*)d_in[12];
  const float* w_s2_2 = (const float*)d_in[13];
  const float* b_s2_2 = (const float*)d_in[14];
  const float* w_c_1 = (const float*)d_in[15];
  const float* b_c_1 = (const float*)d_in[16];
  const float* w_c_2 = (const float*)d_in[17];
  const float* b_c_2 = (const float*)d_in[18];
  const float* attw1 = (const float*)d_in[19];
  const float* attb1 = (const float*)d_in[20];
  const float* attw2 = (const float*)d_in[21];
  const float* mlpw = (const float*)d_in[22];
  const float* mlpb = (const float*)d_in[23];

  const int n = in_sizes[0] / 128;  // 100000
  const int e = in_sizes[1];        // 1600000
  const int vtotal = 2 * n;
  const int nb = (vtotal + BKT_ROWS - 1) >> BKT_BITS;  // 391 buckets

  float* out = (float*)d_out;
  float* o_logp = out;
  float* o_beta = out + (size_t)n * 8;
  float* o_emb1 = out + (size_t)n * 11;
  float* o_com1 = o_emb1 + (size_t)n * 64;
  float* o_com2 = o_com1 + (size_t)n * 64;
  float* o_emb2 = o_com2 + (size_t)n * 64;
  float* o_emb = o_emb2 + (size_t)n * 64;

  // x_bf16 in o_emb region (25.6MB, exact fit); overwritten by final_fuse.
  ushort_t* x_bf16 = (ushort_t*)o_emb;
  // tmp (coarse-bucketed edges) in o_emb1 region: consumed by fine_sort
  // before spmm_dual64 writes o_emb1.
  int2* tmp = (int2*)o_emb1;

  // workspace layout (~78MB)
  ushort_t* ax = (ushort_t*)d_ws;                 // n*128 bf16
  ushort_t* hwI = ax + (size_t)n * 128;           // n*128 bf16 (S|C interleaved)
  ushort_t* w1t_s1 = hwI + (size_t)n * 128;       // 128*128 bf16
  ushort_t* w1t_s2 = w1t_s1 + 16384;
  ushort_t* w1t_c = w1t_s2 + 16384;
  ushort_t* w2t_s1 = w1t_c + 16384;               // 64*128 bf16
  ushort_t* w2t_s2 = w2t_s1 + 8192;
  ushort_t* w2t_c = w2t_s2 + 8192;
  int* rowptr = (int*)(w2t_c + 8192);             // 2n+1
  int* bkt_cnt = rowptr + vtotal + 1;             // nb
  int* bkt_woff = bkt_cnt + nb;                   // nb
  int* bkt_off = bkt_woff + nb;                   // nb+1
  int* tail = bkt_off + nb + 2;                   // align to 8B for int2
  int2* packed = (int2*)(tail + ((((size_t)(tail)&7) == 0) ? 0 : 1));

  const int spmmBlocks = (n + 7) / 8;
  const int cvtBlocks = (int)(((long)n * 32 + 255) / 256);
  const int mfmaBlocks = (n + 63) / 64;

  // one-time preprocessing
  cvt_bf16<<<cvtBlocks, 256, 0, stream>>>(x, x_bf16, (long)n * 32);
  prep_weights<<<288, 256, 0, stream>>>(w_s1_1, w_s2_1, w_c_1, w_s1_2, w_s2_2,
                                        w_c_2, w1t_s1, w1t_s2, w1t_c, w2t_s1,
                                        w2t_s2, w2t_c);

  // two-level counting-sort CSR build (both graphs at once)
  hipMemsetAsync(bkt_cnt, 0, (size_t)(2 * nb) * sizeof(int), stream);
  coarse_hist<<<NBLK1, 256, 0, stream>>>(srow, frow, bkt_cnt, n, e, nb);
  coarse_scan<<<1, 256, 0, stream>>>(bkt_cnt, bkt_off, nb, 2 * e);
  coarse_scatter<<<NBLK1, 256, 0, stream>>>(srow, scol_in, sval_in, frow,
                                            fcol_in, fval_in, bkt_off,
                                            bkt_woff, tmp, n, e, nb);
  fine_sort<<<nb, 256, 0, stream>>>(bkt_off, tmp, packed, rowptr, vtotal,
                                    2 * e);

  const int* rowptrS = rowptr;      // sadj rows: rowptr[0..n]
  const int* rowptrF = rowptr + n;  // fadj rows: rowptr[n..2n]

  // --- graph sadj: emb1 (w_s1) + com1 (w_c) ---
  spmm_csr_128<<<spmmBlocks, 256, 0, stream>>>(rowptrS, packed, x_bf16, ax, n);
  fused_l1l2_mfma_dual<<<mfmaBlocks, 256, 0, stream>>>(
      ax, w1t_s1, b_s1_1, w2t_s1, w1t_c, b_c_1, w2t_c, hwI, n);
  spmm_dual64<<<spmmBlocks, 256, 0, stream>>>(rowptrS, packed, hwI, b_s1_2,
                                              b_c_2, o_emb1, o_com1, n);

  // --- graph fadj: com2 (w_c) + emb2 (w_s2) ---
  spmm_csr_128<<<spmmBlocks, 256, 0, stream>>>(rowptrF, packed, x_bf16, ax, n);
  fused_l1l2_mfma_dual<<<mfmaBlocks, 256, 0, stream>>>(
      ax, w1t_s2, b_s2_1, w2t_s2, w1t_c, b_c_1, w2t_c, hwI, n);
  spmm_dual64<<<spmmBlocks, 256, 0, stream>>>(rowptrF, packed, hwI, b_s2_2,
                                              b_c_2, o_emb2, o_com2, n);

  final_fuse<<<(int)(((long)n * 16 + 255) / 256), 256, 0, stream>>>(
      o_emb1, o_emb2, o_com1, o_com2, attw1, attb1, attw2, mlpw, mlpb, o_logp,
      o_beta, o_emb, n);
}

// Round 16
// 591.691 us; speedup vs baseline: 1.0174x; 1.0174x over previous
//
#include <hip/hip_runtime.h>

// ---------------------------------------------------------------------------
// SFGCN forward on MI355X, round 16:
//  - Sort geometry FIX (round-15 lesson: run length = edges/block/buckets;
//    occupancy was not the constraint): NBLK1 back to 512, buckets widened to
//    1024 rows (196 total) -> ~32-edge (256B, full-cacheline) runs per
//    (block,bucket) in coarse_scatter. fine_sort handles 1024-row windows.
//  - hw interleaved [n][128], MFMA dense chain, reduce-scatter final_fuse,
//    bf16 gathers unchanged (round-15 state).
// ---------------------------------------------------------------------------

typedef unsigned short ushort_t;
typedef float f32x4 __attribute__((ext_vector_type(4)));
typedef short short8 __attribute__((ext_vector_type(8)));

#define NBLK1 512        // blocks for coarse hist/scatter (grid-stride)
#define BKT_BITS 10      // 1024 rows per coarse bucket
#define BKT_ROWS 1024

__device__ __forceinline__ ushort_t f2bf(float f) {  // round-to-nearest-even
  unsigned u = __float_as_uint(f);
  unsigned r = (u + 0x7FFFu + ((u >> 16) & 1u)) >> 16;
  return (ushort_t)r;
}
__device__ __forceinline__ float bf2f(ushort_t b) {
  return __uint_as_float((unsigned)b << 16);
}

// reduce-scatter 16 values across a 16-lane group: lane ends with the full
// 16-lane sum of element [lane&15]. 15 shfl, compile-time register indices.
__device__ __forceinline__ float rs16(const float a[16], int lane) {
  bool b8 = (lane & 8) != 0;
  float t[8];
#pragma unroll
  for (int j = 0; j < 8; ++j) {
    float sent = b8 ? a[j] : a[j + 8];
    float mine = b8 ? a[j + 8] : a[j];
    t[j] = mine + __shfl_xor(sent, 8);
  }
  bool b4 = (lane & 4) != 0;
  float u[4];
#pragma unroll
  for (int j = 0; j < 4; ++j) {
    float sent = b4 ? t[j] : t[j + 4];
    float mine = b4 ? t[j + 4] : t[j];
    u[j] = mine + __shfl_xor(sent, 4);
  }
  bool b2 = (lane & 2) != 0;
  float v[2];
#pragma unroll
  for (int j = 0; j < 2; ++j) {
    float s2 = b2 ? u[j] : u[j + 2];
    float m2 = b2 ? u[j + 2] : u[j];
    v[j] = m2 + __shfl_xor(s2, 2);
  }
  bool b1 = (lane & 1) != 0;
  float s1 = b1 ? v[0] : v[1];
  float m1 = b1 ? v[1] : v[0];
  return m1 + __shfl_xor(s1, 1);
}

// total4 float4 chunks -> ushort4 bf16 chunks
__global__ __launch_bounds__(256) void cvt_bf16(
    const float* __restrict__ in, ushort_t* __restrict__ out, long total4) {
  long i = (long)blockIdx.x * 256 + threadIdx.x;
  if (i >= total4) return;
  float4 v = ((const float4*)in)[i];
  ushort4 o;
  o.x = f2bf(v.x);
  o.y = f2bf(v.y);
  o.z = f2bf(v.z);
  o.w = f2bf(v.w);
  ((ushort4*)out)[i] = o;
}

// Transpose+cast the 3 weight pairs to bf16.
__global__ __launch_bounds__(256) void prep_weights(
    const float* __restrict__ w1a, const float* __restrict__ w1b,
    const float* __restrict__ w1c, const float* __restrict__ w2a,
    const float* __restrict__ w2b, const float* __restrict__ w2c,
    ushort_t* __restrict__ o1a, ushort_t* __restrict__ o1b,
    ushort_t* __restrict__ o1c, ushort_t* __restrict__ o2a,
    ushort_t* __restrict__ o2b, ushort_t* __restrict__ o2c) {
  int i = blockIdx.x * 256 + threadIdx.x;
  if (i < 49152) {  // 3 x 128x128
    int a = i >> 14, j = i & 16383;
    int nn = j >> 7, k = j & 127;
    const float* s = (a == 0) ? w1a : (a == 1) ? w1b : w1c;
    ushort_t* d = (a == 0) ? o1a : (a == 1) ? o1b : o1c;
    d[j] = f2bf(s[k * 128 + nn]);
  } else if (i < 73728) {  // 3 x 64x128
    int i2 = i - 49152;
    int a = i2 >> 13, j = i2 & 8191;
    int h = j >> 7, k = j & 127;
    const float* s = (a == 0) ? w2a : (a == 1) ? w2b : w2c;
    ushort_t* d = (a == 0) ? o2a : (a == 1) ? o2b : o2c;
    d[j] = f2bf(s[k * 64 + h]);
  }
}

// ---------------- two-level counting sort CSR build ----------------
// vrow in [0, 2n); bucket = vrow >> BKT_BITS (196 buckets of 1024 rows).

__global__ __launch_bounds__(256) void coarse_hist(
    const int* __restrict__ rowS, const int* __restrict__ rowF,
    int* __restrict__ bkt_cnt, int n, int e, int nb) {
  __shared__ int lh[200];
  int t = threadIdx.x;
  for (int j = t; j < nb; j += 256) lh[j] = 0;
  __syncthreads();
  long total = 2L * e;
  long stride = (long)NBLK1 * 256;
  for (long i = (long)blockIdx.x * 256 + t; i < total; i += stride) {
    int vrow = (i < e) ? rowS[i] : (n + rowF[i - e]);
    atomicAdd(&lh[vrow >> BKT_BITS], 1);
  }
  __syncthreads();
  for (int j = t; j < nb; j += 256)
    if (lh[j]) atomicAdd(&bkt_cnt[j], lh[j]);
}

__global__ __launch_bounds__(256) void coarse_scan(
    const int* __restrict__ cnt, int* __restrict__ off, int nb, int total) {
  __shared__ int lds[256];
  int t = threadIdx.x;
  int c[4];
  int s = 0;
#pragma unroll
  for (int j = 0; j < 4; ++j) {
    int idx = t * 4 + j;
    c[j] = (idx < nb) ? cnt[idx] : 0;
    s += c[j];
  }
  lds[t] = s;
  __syncthreads();
#pragma unroll
  for (int d = 1; d < 256; d <<= 1) {
    int v = (t >= d) ? lds[t - d] : 0;
    __syncthreads();
    lds[t] += v;
    __syncthreads();
  }
  int o = (t == 0) ? 0 : lds[t - 1];
#pragma unroll
  for (int j = 0; j < 4; ++j) {
    int idx = t * 4 + j;
    if (idx < nb) off[idx] = o;
    o += c[j];
  }
  if (t == 0) off[nb] = total;
}

// tmp[p] = (col | vlow<<20, val_bits); col < 2^20, vlow = vrow & 1023.
__global__ __launch_bounds__(256) void coarse_scatter(
    const int* __restrict__ rowS, const int* __restrict__ colS,
    const float* __restrict__ valS, const int* __restrict__ rowF,
    const int* __restrict__ colF, const float* __restrict__ valF,
    const int* __restrict__ bkt_off, int* __restrict__ bkt_woff,
    int2* __restrict__ tmp, int n, int e, int nb) {
  __shared__ int lh[200];
  __shared__ int lb[200];
  __shared__ int gb[200];
  int t = threadIdx.x;
  for (int j = t; j < nb; j += 256) {
    lh[j] = 0;
    lb[j] = 0;
  }
  __syncthreads();
  long total = 2L * e;
  long stride = (long)NBLK1 * 256;
  for (long i = (long)blockIdx.x * 256 + t; i < total; i += stride) {
    int vrow = (i < e) ? rowS[i] : (n + rowF[i - e]);
    atomicAdd(&lh[vrow >> BKT_BITS], 1);
  }
  __syncthreads();
  for (int j = t; j < nb; j += 256) {
    int h = lh[j];
    gb[j] = h ? (bkt_off[j] + atomicAdd(&bkt_woff[j], h)) : 0;
  }
  __syncthreads();
  for (long i = (long)blockIdx.x * 256 + t; i < total; i += stride) {
    int vrow, c;
    float v;
    if (i < e) {
      vrow = rowS[i];
      c = colS[i];
      v = valS[i];
    } else {
      vrow = n + rowF[i - e];
      c = colF[i - e];
      v = valF[i - e];
    }
    int b = vrow >> BKT_BITS;
    int k = atomicAdd(&lb[b], 1);
    tmp[gb[b] + k] =
        make_int2(c | ((vrow & (BKT_ROWS - 1)) << 20), __float_as_int(v));
  }
}

// one block per 1024-row bucket: LDS hist + scan -> rowptr, then scatter
// within the bucket's ~131KB window (L2-resident).
__global__ __launch_bounds__(256) void fine_sort(
    const int* __restrict__ bkt_off, const int2* __restrict__ tmp,
    int2* __restrict__ packed, int* __restrict__ rowptr, int vtotal,
    int etotal) {
  __shared__ int hist[1024];
  __shared__ int scn[256];
  __shared__ int rowb[1024];
  __shared__ int bump[1024];
  int b = blockIdx.x;
  int t = threadIdx.x;
  int lo = bkt_off[b], hi = bkt_off[b + 1];
#pragma unroll
  for (int j = 0; j < 4; ++j) {
    hist[t + 256 * j] = 0;
    bump[t + 256 * j] = 0;
  }
  __syncthreads();
  for (int i = lo + t; i < hi; i += 256)
    atomicAdd(&hist[((unsigned)tmp[i].x) >> 20], 1);
  __syncthreads();
  int h0 = hist[4 * t], h1 = hist[4 * t + 1], h2 = hist[4 * t + 2],
      h3 = hist[4 * t + 3];
  scn[t] = h0 + h1 + h2 + h3;
  __syncthreads();
#pragma unroll
  for (int d = 1; d < 256; d <<= 1) {
    int v = (t >= d) ? scn[t - d] : 0;
    __syncthreads();
    scn[t] += v;
    __syncthreads();
  }
  int pre = (t == 0) ? 0 : scn[t - 1];
  int r0 = lo + pre;
  int r1 = r0 + h0;
  int r2 = r1 + h1;
  int r3 = r2 + h2;
  rowb[4 * t] = r0;
  rowb[4 * t + 1] = r1;
  rowb[4 * t + 2] = r2;
  rowb[4 * t + 3] = r3;
  int vrow0 = b * BKT_ROWS + 4 * t;
  if (vrow0 < vtotal) rowptr[vrow0] = r0;
  if (vrow0 + 1 < vtotal) rowptr[vrow0 + 1] = r1;
  if (vrow0 + 2 < vtotal) rowptr[vrow0 + 2] = r2;
  if (vrow0 + 3 < vtotal) rowptr[vrow0 + 3] = r3;
  __syncthreads();
  for (int i = lo + t; i < hi; i += 256) {
    int2 p = tmp[i];
    int vl = ((unsigned)p.x) >> 20;
    int dest = rowb[vl] + atomicAdd(&bump[vl], 1);
    packed[dest] = make_int2(p.x & 0xFFFFF, p.y);
  }
  if (b == 0 && t == 0) rowptr[vtotal] = etotal;
}

// ---------------- CSR SpMM (bf16 gather, fp32 accumulate) ----------------

__global__ __launch_bounds__(256) void spmm_csr_128(
    const int* __restrict__ rowptr, const int2* __restrict__ packed,
    const ushort_t* __restrict__ h, ushort_t* __restrict__ Ax, int n) {
  int tid = threadIdx.x;
  int r = blockIdx.x * 8 + (tid >> 5);
  if (r >= n) return;
  int lane = tid & 31;
  int lo = rowptr[r], hi = rowptr[r + 1];
  const ushort4* h4 = (const ushort4*)h;  // row stride = 32 ushort4
  float4 acc = make_float4(0.f, 0.f, 0.f, 0.f);
  int e = lo;
  for (; e + 4 <= hi; e += 4) {
    int2 p0 = packed[e], p1 = packed[e + 1], p2 = packed[e + 2],
         p3 = packed[e + 3];
    float v0 = __int_as_float(p0.y), v1 = __int_as_float(p1.y),
          v2 = __int_as_float(p2.y), v3 = __int_as_float(p3.y);
    ushort4 q0 = h4[(long)p0.x * 32 + lane];
    ushort4 q1 = h4[(long)p1.x * 32 + lane];
    ushort4 q2 = h4[(long)p2.x * 32 + lane];
    ushort4 q3 = h4[(long)p3.x * 32 + lane];
    acc.x += v0 * bf2f(q0.x) + v1 * bf2f(q1.x) + v2 * bf2f(q2.x) + v3 * bf2f(q3.x);
    acc.y += v0 * bf2f(q0.y) + v1 * bf2f(q1.y) + v2 * bf2f(q2.y) + v3 * bf2f(q3.y);
    acc.z += v0 * bf2f(q0.z) + v1 * bf2f(q1.z) + v2 * bf2f(q2.z) + v3 * bf2f(q3.z);
    acc.w += v0 * bf2f(q0.w) + v1 * bf2f(q1.w) + v2 * bf2f(q2.w) + v3 * bf2f(q3.w);
  }
  for (; e < hi; ++e) {
    int2 p = packed[e];
    float v = __int_as_float(p.y);
    ushort4 q = h4[(long)p.x * 32 + lane];
    acc.x += v * bf2f(q.x);
    acc.y += v * bf2f(q.y);
    acc.z += v * bf2f(q.z);
    acc.w += v * bf2f(q.w);
  }
  ushort4 o;
  o.x = f2bf(acc.x);
  o.y = f2bf(acc.y);
  o.z = f2bf(acc.z);
  o.w = f2bf(acc.w);
  ((ushort4*)Ax)[(long)r * 32 + lane] = o;
}

// Dual 64-feat SpMM over INTERLEAVED hI[n][128] (S=0..63, C=64..127):
// one 256B contiguous row gather per edge; lanes 0-15 -> S, 16-31 -> C.
__global__ __launch_bounds__(256) void spmm_dual64(
    const int* __restrict__ rowptr, const int2* __restrict__ packed,
    const ushort_t* __restrict__ hI, const float* __restrict__ bS,
    const float* __restrict__ bC, float* __restrict__ outS,
    float* __restrict__ outC, int n) {
  int tid = threadIdx.x;
  int r = blockIdx.x * 8 + (tid >> 5);
  if (r >= n) return;
  int lane = tid & 31;
  int half = lane >> 4;
  int li = lane & 15;
  const ushort4* h4 = (const ushort4*)hI;  // row = 32 ushort4 (S|C)
  float4 acc = ((const float4*)(half ? bC : bS))[li];
  int lo = rowptr[r], hi = rowptr[r + 1];
  int e = lo;
  for (; e + 4 <= hi; e += 4) {
    int2 p0 = packed[e], p1 = packed[e + 1], p2 = packed[e + 2],
         p3 = packed[e + 3];
    float v0 = __int_as_float(p0.y), v1 = __int_as_float(p1.y),
          v2 = __int_as_float(p2.y), v3 = __int_as_float(p3.y);
    ushort4 q0 = h4[(long)p0.x * 32 + lane];
    ushort4 q1 = h4[(long)p1.x * 32 + lane];
    ushort4 q2 = h4[(long)p2.x * 32 + lane];
    ushort4 q3 = h4[(long)p3.x * 32 + lane];
    acc.x += v0 * bf2f(q0.x) + v1 * bf2f(q1.x) + v2 * bf2f(q2.x) + v3 * bf2f(q3.x);
    acc.y += v0 * bf2f(q0.y) + v1 * bf2f(q1.y) + v2 * bf2f(q2.y) + v3 * bf2f(q3.y);
    acc.z += v0 * bf2f(q0.z) + v1 * bf2f(q1.z) + v2 * bf2f(q2.z) + v3 * bf2f(q3.z);
    acc.w += v0 * bf2f(q0.w) + v1 * bf2f(q1.w) + v2 * bf2f(q2.w) + v3 * bf2f(q3.w);
  }
  for (; e < hi; ++e) {
    int2 p = packed[e];
    float v = __int_as_float(p.y);
    ushort4 q = h4[(long)p.x * 32 + lane];
    acc.x += v * bf2f(q.x);
    acc.y += v * bf2f(q.y);
    acc.z += v * bf2f(q.z);
    acc.w += v * bf2f(q.w);
  }
  float4* o = (float4*)(half ? outC : outS);
  o[(long)r * 16 + li] = acc;
}

// ---------------- fused dense chain, bf16 MFMA, dual weight sets ----------
// Writes into interleaved HI[n][128] at feature offset hoff (0 or 64).
__device__ __forceinline__ void l1l2_chain(
    const ushort_t* __restrict__ Ax, const ushort_t* __restrict__ W1T,
    const float* __restrict__ B1, const ushort_t* __restrict__ W2T,
    ushort_t* __restrict__ HI, int hoff, int n, long node0, int w, int lo16,
    int g, ushort_t (*sp)[136]) {
  // ---- GEMM1 (flipped): S^T = W1T x Ax^T ----
  f32x4 acc1[2][4];
#pragma unroll
  for (int m = 0; m < 2; ++m)
#pragma unroll
    for (int nu = 0; nu < 4; ++nu) acc1[m][nu] = (f32x4){0.f, 0.f, 0.f, 0.f};

#pragma unroll 1
  for (int t = 0; t < 4; ++t) {
    short8 af0 = *(const short8*)(W1T + (32 * w + lo16) * 128 + 32 * t + 8 * g);
    short8 af1 =
        *(const short8*)(W1T + (32 * w + 16 + lo16) * 128 + 32 * t + 8 * g);
#pragma unroll
    for (int nu = 0; nu < 4; ++nu) {
      long node = node0 + 16 * nu + lo16;
      if (node > (long)n - 1) node = (long)n - 1;
      short8 bf = *(const short8*)(Ax + node * 128 + 32 * t + 8 * g);
      acc1[0][nu] =
          __builtin_amdgcn_mfma_f32_16x16x32_bf16(af0, bf, acc1[0][nu], 0, 0, 0);
      acc1[1][nu] =
          __builtin_amdgcn_mfma_f32_16x16x32_bf16(af1, bf, acc1[1][nu], 0, 0, 0);
    }
  }

  // relu + bias, pack 4 contiguous sfeats -> S' LDS
#pragma unroll
  for (int m = 0; m < 2; ++m) {
    int sf = 32 * w + 16 * m + 4 * g;
    float4 b1v = *(const float4*)(B1 + sf);
#pragma unroll
    for (int nu = 0; nu < 4; ++nu) {
      int node_l = 16 * nu + lo16;
      ushort4 pk;
      pk.x = f2bf(fmaxf(acc1[m][nu][0] + b1v.x, 0.f));
      pk.y = f2bf(fmaxf(acc1[m][nu][1] + b1v.y, 0.f));
      pk.z = f2bf(fmaxf(acc1[m][nu][2] + b1v.z, 0.f));
      pk.w = f2bf(fmaxf(acc1[m][nu][3] + b1v.w, 0.f));
      *(ushort4*)(&sp[node_l][sf]) = pk;
    }
  }
  __syncthreads();

  // ---- GEMM2 (standard): H = S' @ W2 ----
  f32x4 acc2[4];
#pragma unroll
  for (int nu = 0; nu < 4; ++nu) acc2[nu] = (f32x4){0.f, 0.f, 0.f, 0.f};
#pragma unroll 1
  for (int t = 0; t < 4; ++t) {
    short8 af = *(const short8*)(&sp[16 * w + lo16][32 * t + 8 * g]);
#pragma unroll
    for (int nu = 0; nu < 4; ++nu) {
      short8 bf =
          *(const short8*)(W2T + (16 * nu + lo16) * 128 + 32 * t + 8 * g);
      acc2[nu] =
          __builtin_amdgcn_mfma_f32_16x16x32_bf16(af, bf, acc2[nu], 0, 0, 0);
    }
  }
#pragma unroll
  for (int nu = 0; nu < 4; ++nu) {
#pragma unroll
    for (int r = 0; r < 4; ++r) {
      long node = node0 + 16 * w + 4 * g + r;
      if (node < n) HI[node * 128 + hoff + 16 * nu + lo16] = f2bf(acc2[nu][r]);
    }
  }
}

__global__ __launch_bounds__(256) void fused_l1l2_mfma_dual(
    const ushort_t* __restrict__ Ax, const ushort_t* __restrict__ W1Ta,
    const float* __restrict__ B1a, const ushort_t* __restrict__ W2Ta,
    const ushort_t* __restrict__ W1Tb, const float* __restrict__ B1b,
    const ushort_t* __restrict__ W2Tb, ushort_t* __restrict__ HI, int n) {
  __shared__ __attribute__((aligned(16))) ushort_t sp[64][136];
  int tid = threadIdx.x;
  int w = tid >> 6;
  int l = tid & 63;
  int lo16 = l & 15;
  int g = l >> 4;
  long node0 = (long)blockIdx.x * 64;

  l1l2_chain(Ax, W1Ta, B1a, W2Ta, HI, 0, n, node0, w, lo16, g, sp);
  __syncthreads();  // WAR on sp before chain B overwrites
  l1l2_chain(Ax, W1Tb, B1b, W2Tb, HI, 64, n, node0, w, lo16, g, sp);
}

// ---------------- final fuse v3 (reduce-scatter; 16 lanes per node) -------
__global__ __launch_bounds__(256) void final_fuse(
    const float* __restrict__ emb1, const float* __restrict__ emb2,
    const float* __restrict__ com1, const float* __restrict__ com2,
    const float* __restrict__ attw1, const float* __restrict__ attb1,
    const float* __restrict__ attw2, const float* __restrict__ mlpw,
    const float* __restrict__ mlpb, float* __restrict__ out_logp,
    float* __restrict__ out_beta, float* __restrict__ out_emb, int n) {
  __shared__ __attribute__((aligned(16))) float w1t[16][64];
  __shared__ __attribute__((aligned(16))) float mwt[8][64];
  __shared__ float b1s[16];
  __shared__ float w2s[16];
  __shared__ float mbs[8];
  int tid = threadIdx.x;
  for (int idx = tid; idx < 1024; idx += 256)
    w1t[idx & 15][idx >> 4] = attw1[idx];
  for (int idx = tid; idx < 512; idx += 256)
    mwt[idx & 7][idx >> 3] = mlpw[idx];
  if (tid < 16) {
    b1s[tid] = attb1[tid];
    w2s[tid] = attw2[tid];
  }
  if (tid < 8) mbs[tid] = mlpb[tid];
  __syncthreads();

  int lane = tid & 15;
  long i = ((long)blockIdx.x * 256 + tid) >> 4;
  bool alive = i < n;
  long ii = alive ? i : (long)(n - 1);

  float4 z0 = ((const float4*)emb1)[ii * 16 + lane];
  float4 z1 = ((const float4*)emb2)[ii * 16 + lane];
  float4 x1 = ((const float4*)com1)[ii * 16 + lane];
  float4 x2 = ((const float4*)com2)[ii * 16 + lane];
  float4 z2 = make_float4(0.5f * (x1.x + x2.x), 0.5f * (x1.y + x2.y),
                          0.5f * (x1.z + x2.z), 0.5f * (x1.w + x2.w));

  // attention partials
  float a0[16], a1[16], a2[16];
#pragma unroll
  for (int m = 0; m < 16; ++m) {
    float4 w = *(const float4*)&w1t[m][lane * 4];
    a0[m] = z0.x * w.x + z0.y * w.y + z0.z * w.z + z0.w * w.w;
    a1[m] = z1.x * w.x + z1.y * w.y + z1.z * w.z + z1.w * w.w;
    a2[m] = z2.x * w.x + z2.y * w.y + z2.z * w.z + z2.w * w.w;
  }
  // reduce-scatter: lane owns unit m = lane
  float A0 = rs16(a0, lane);
  float A1 = rs16(a1, lane);
  float A2 = rs16(a2, lane);
  // per-lane tanh (3 instead of 48), then all-reduce of the 3 scores
  float bm = b1s[lane], wm = w2s[lane];
  float p0 = tanhf(A0 + bm) * wm;
  float p1 = tanhf(A1 + bm) * wm;
  float p2 = tanhf(A2 + bm) * wm;
#pragma unroll
  for (int d = 1; d < 16; d <<= 1) {
    p0 += __shfl_xor(p0, d);
    p1 += __shfl_xor(p1, d);
    p2 += __shfl_xor(p2, d);
  }
  float mx = fmaxf(p0, fmaxf(p1, p2));
  float ex0 = expf(p0 - mx), ex1 = expf(p1 - mx), ex2 = expf(p2 - mx);
  float inv = 1.f / (ex0 + ex1 + ex2);
  float be0 = ex0 * inv, be1 = ex1 * inv, be2 = ex2 * inv;

  float4 em;
  em.x = be0 * z0.x + be1 * z1.x + be2 * z2.x;
  em.y = be0 * z0.y + be1 * z1.y + be2 * z2.y;
  em.z = be0 * z0.z + be1 * z1.z + be2 * z2.z;
  em.w = be0 * z0.w + be1 * z1.w + be2 * z2.w;
  if (alive) ((float4*)out_emb)[i * 16 + lane] = em;

  // logits partials
  float lg[8];
#pragma unroll
  for (int p = 0; p < 8; ++p) {
    float4 w = *(const float4*)&mwt[p][lane * 4];
    lg[p] = em.x * w.x + em.y * w.y + em.z * w.z + em.w * w.w;
  }
  // reduce-scatter 8 elements over 16 lanes; owner index = 4*b8 + 2*b4 + b2,
  // then the bit-0 pair exchange completes the 16-lane sum.
  bool b8 = (lane & 8) != 0;
  float t4[4];
#pragma unroll
  for (int j = 0; j < 4; ++j) {
    float sent = b8 ? lg[j] : lg[j + 4];
    float mine = b8 ? lg[j + 4] : lg[j];
    t4[j] = mine + __shfl_xor(sent, 8);
  }
  bool b4 = (lane & 4) != 0;
  float t2[2];
#pragma unroll
  for (int j = 0; j < 2; ++j) {
    float sent = b4 ? t4[j] : t4[j + 2];
    float mine = b4 ? t4[j + 2] : t4[j];
    t2[j] = mine + __shfl_xor(sent, 4);
  }
  bool b2 = (lane & 2) != 0;
  {
    float sent = b2 ? t2[0] : t2[1];
    float mine = b2 ? t2[1] : t2[0];
    t2[0] = mine + __shfl_xor(sent, 2);
  }
  t2[0] += __shfl_xor(t2[0], 1);  // lanes l, l^1 hold complementary halves
  int myidx = (b8 ? 4 : 0) + (b4 ? 2 : 0) + (b2 ? 1 : 0);
  float lgv = t2[0] + mbs[myidx];
  // all-reduce max & sum over the 8 distinct indices (d = 2,4,8)
  float m2 = lgv;
  m2 = fmaxf(m2, __shfl_xor(m2, 2));
  m2 = fmaxf(m2, __shfl_xor(m2, 4));
  m2 = fmaxf(m2, __shfl_xor(m2, 8));
  float ev = expf(lgv - m2);
  float ssum = ev;
  ssum += __shfl_xor(ssum, 2);
  ssum += __shfl_xor(ssum, 4);
  ssum += __shfl_xor(ssum, 8);
  float ls = m2 + logf(ssum);

  if (alive) {
    if ((lane & 1) == 0) out_logp[i * 8 + myidx] = lgv - ls;
    if (lane == 0) {
      out_beta[i * 3 + 0] = be0;
      out_beta[i * 3 + 1] = be1;
      out_beta[i * 3 + 2] = be2;
    }
  }
}

extern "C" void kernel_launch(void* const* d_in, const int* in_sizes, int n_in,
                              void* d_out, int out_size, void* d_ws,
                              size_t ws_size, hipStream_t stream) {
  const float* x = (const float*)d_in[0];
  const int* srow = (const int*)d_in[1];
  const int* scol_in = (const int*)d_in[2];
  const float* sval_in = (const float*)d_in[3];
  const int* frow = (const int*)d_in[4];
  const int* fcol_in = (const int*)d_in[5];
  const float* fval_in = (const float*)d_in[6];
  const float* w_s1_1 = (const float*)d_in[7];
  const float* b_s1_1 = (const float*)d_in[8];
  const float* w_s1_2 = (const float*)d_in[9];
  const float* b_s1_2 = (const float*)d_in[10];
  const float* w_s2_1 = (const float*)d_in[11];
  const float* b_s2_1 = (const float*)d_in[12];
  const float* w_s2_2 = (const float*)d_in[13];
  const float* b_s2_2 = (const float*)d_in[14];
  const float* w_c_1 = (const float*)d_in[15];
  const float* b_c_1 = (const float*)d_in[16];
  const float* w_c_2 = (const float*)d_in[17];
  const float* b_c_2 = (const float*)d_in[18];
  const float* attw1 = (const float*)d_in[19];
  const float* attb1 = (const float*)d_in[20];
  const float* attw2 = (const float*)d_in[21];
  const float* mlpw = (const float*)d_in[22];
  const float* mlpb = (const float*)d_in[23];

  const int n = in_sizes[0] / 128;  // 100000
  const int e = in_sizes[1];        // 1600000
  const int vtotal = 2 * n;
  const int nb = (vtotal + BKT_ROWS - 1) >> BKT_BITS;  // 196 buckets

  float* out = (float*)d_out;
  float* o_logp = out;
  float* o_beta = out + (size_t)n * 8;
  float* o_emb1 = out + (size_t)n * 11;
  float* o_com1 = o_emb1 + (size_t)n * 64;
  float* o_com2 = o_com1 + (size_t)n * 64;
  float* o_emb2 = o_com2 + (size_t)n * 64;
  float* o_emb = o_emb2 + (size_t)n * 64;

  // x_bf16 in o_emb region (25.6MB, exact fit); overwritten by final_fuse.
  ushort_t* x_bf16 = (ushort_t*)o_emb;
  // tmp (coarse-bucketed edges) in o_emb1 region: consumed by fine_sort
  // before spmm_dual64 writes o_emb1.
  int2* tmp = (int2*)o_emb1;

  // workspace layout (~78MB)
  ushort_t* ax = (ushort_t*)d_ws;                 // n*128 bf16
  ushort_t* hwI = ax + (size_t)n * 128;           // n*128 bf16 (S|C interleaved)
  ushort_t* w1t_s1 = hwI + (size_t)n * 128;       // 128*128 bf16
  ushort_t* w1t_s2 = w1t_s1 + 16384;
  ushort_t* w1t_c = w1t_s2 + 16384;
  ushort_t* w2t_s1 = w1t_c + 16384;               // 64*128 bf16
  ushort_t* w2t_s2 = w2t_s1 + 8192;
  ushort_t* w2t_c = w2t_s2 + 8192;
  int* rowptr = (int*)(w2t_c + 8192);             // 2n+1
  int* bkt_cnt = rowptr + vtotal + 1;             // nb
  int* bkt_woff = bkt_cnt + nb;                   // nb
  int* bkt_off = bkt_woff + nb;                   // nb+1
  int* tail = bkt_off + nb + 2;                   // align to 8B for int2
  int2* packed = (int2*)(tail + ((((size_t)(tail)&7) == 0) ? 0 : 1));

  const int spmmBlocks = (n + 7) / 8;
  const int cvtBlocks = (int)(((long)n * 32 + 255) / 256);
  const int mfmaBlocks = (n + 63) / 64;

  // one-time preprocessing
  cvt_bf16<<<cvtBlocks, 256, 0, stream>>>(x, x_bf16, (long)n * 32);
  prep_weights<<<288, 256, 0, stream>>>(w_s1_1, w_s2_1, w_c_1, w_s1_2, w_s2_2,
                                        w_c_2, w1t_s1, w1t_s2, w1t_c, w2t_s1,
                                        w2t_s2, w2t_c);

  // two-level counting-sort CSR build (both graphs at once)
  hipMemsetAsync(bkt_cnt, 0, (size_t)(2 * nb) * sizeof(int), stream);
  coarse_hist<<<NBLK1, 256, 0, stream>>>(srow, frow, bkt_cnt, n, e, nb);
  coarse_scan<<<1, 256, 0, stream>>>(bkt_cnt, bkt_off, nb, 2 * e);
  coarse_scatter<<<NBLK1, 256, 0, stream>>>(srow, scol_in, sval_in, frow,
                                            fcol_in, fval_in, bkt_off,
                                            bkt_woff, tmp, n, e, nb);
  fine_sort<<<nb, 256, 0, stream>>>(bkt_off, tmp, packed, rowptr, vtotal,
                                    2 * e);

  const int* rowptrS = rowptr;      // sadj rows: rowptr[0..n]
  const int* rowptrF = rowptr + n;  // fadj rows: rowptr[n..2n]

  // --- graph sadj: emb1 (w_s1) + com1 (w_c) ---
  spmm_csr_128<<<spmmBlocks, 256, 0, stream>>>(rowptrS, packed, x_bf16, ax, n);
  fused_l1l2_mfma_dual<<<mfmaBlocks, 256, 0, stream>>>(
      ax, w1t_s1, b_s1_1, w2t_s1, w1t_c, b_c_1, w2t_c, hwI, n);
  spmm_dual64<<<spmmBlocks, 256, 0, stream>>>(rowptrS, packed, hwI, b_s1_2,
                                              b_c_2, o_emb1, o_com1, n);

  // --- graph fadj: com2 (w_c) + emb2 (w_s2) ---
  spmm_csr_128<<<spmmBlocks, 256, 0, stream>>>(rowptrF, packed, x_bf16, ax, n);
  fused_l1l2_mfma_dual<<<mfmaBlocks, 256, 0, stream>>>(
      ax, w1t_s2, b_s2_1, w2t_s2, w1t_c, b_c_1, w2t_c, hwI, n);
  spmm_dual64<<<spmmBlocks, 256, 0, stream>>>(rowptrF, packed, hwI, b_s2_2,
                                              b_c_2, o_emb2, o_com2, n);

  final_fuse<<<(int)(((long)n * 16 + 255) / 256), 256, 0, stream>>>(
      o_emb1, o_emb2, o_com1, o_com2, attw1, attb1, attw2, mlpw, mlpb, o_logp,
      o_beta, o_emb, n);
}

// Round 17
// 557.431 us; speedup vs baseline: 1.0800x; 1.0615x over previous
//
#include <hip/hip_runtime.h>

// ---------------------------------------------------------------------------
// SFGCN forward on MI355X, round 17:
//  - SINGLE-PASS coarse_scatter (round-16 lesson: scatter was latency-bound
//    on its two passes, not write-bound). coarse_hist now exports its
//    per-(block,bucket) histogram (block-major, coalesced); new blk_scan
//    turns it into absolute base addresses; coarse_scatter drops its hist
//    pass (halves its latency chains, -12.8MB reads, no reservation atomics).
//  - 1024-row buckets, interleaved hw, MFMA chain, reduce-scatter final_fuse
//    unchanged (round-16 state).
// ---------------------------------------------------------------------------

typedef unsigned short ushort_t;
typedef float f32x4 __attribute__((ext_vector_type(4)));
typedef short short8 __attribute__((ext_vector_type(8)));

#define NBLK1 512        // blocks for coarse hist/scatter (grid-stride)
#define BKT_BITS 10      // 1024 rows per coarse bucket
#define BKT_ROWS 1024

__device__ __forceinline__ ushort_t f2bf(float f) {  // round-to-nearest-even
  unsigned u = __float_as_uint(f);
  unsigned r = (u + 0x7FFFu + ((u >> 16) & 1u)) >> 16;
  return (ushort_t)r;
}
__device__ __forceinline__ float bf2f(ushort_t b) {
  return __uint_as_float((unsigned)b << 16);
}

// reduce-scatter 16 values across a 16-lane group: lane ends with the full
// 16-lane sum of element [lane&15]. 15 shfl, compile-time register indices.
__device__ __forceinline__ float rs16(const float a[16], int lane) {
  bool b8 = (lane & 8) != 0;
  float t[8];
#pragma unroll
  for (int j = 0; j < 8; ++j) {
    float sent = b8 ? a[j] : a[j + 8];
    float mine = b8 ? a[j + 8] : a[j];
    t[j] = mine + __shfl_xor(sent, 8);
  }
  bool b4 = (lane & 4) != 0;
  float u[4];
#pragma unroll
  for (int j = 0; j < 4; ++j) {
    float sent = b4 ? t[j] : t[j + 4];
    float mine = b4 ? t[j + 4] : t[j];
    u[j] = mine + __shfl_xor(sent, 4);
  }
  bool b2 = (lane & 2) != 0;
  float v[2];
#pragma unroll
  for (int j = 0; j < 2; ++j) {
    float s2 = b2 ? u[j] : u[j + 2];
    float m2 = b2 ? u[j + 2] : u[j];
    v[j] = m2 + __shfl_xor(s2, 2);
  }
  bool b1 = (lane & 1) != 0;
  float s1 = b1 ? v[0] : v[1];
  float m1 = b1 ? v[1] : v[0];
  return m1 + __shfl_xor(s1, 1);
}

// total4 float4 chunks -> ushort4 bf16 chunks
__global__ __launch_bounds__(256) void cvt_bf16(
    const float* __restrict__ in, ushort_t* __restrict__ out, long total4) {
  long i = (long)blockIdx.x * 256 + threadIdx.x;
  if (i >= total4) return;
  float4 v = ((const float4*)in)[i];
  ushort4 o;
  o.x = f2bf(v.x);
  o.y = f2bf(v.y);
  o.z = f2bf(v.z);
  o.w = f2bf(v.w);
  ((ushort4*)out)[i] = o;
}

// Transpose+cast the 3 weight pairs to bf16.
__global__ __launch_bounds__(256) void prep_weights(
    const float* __restrict__ w1a, const float* __restrict__ w1b,
    const float* __restrict__ w1c, const float* __restrict__ w2a,
    const float* __restrict__ w2b, const float* __restrict__ w2c,
    ushort_t* __restrict__ o1a, ushort_t* __restrict__ o1b,
    ushort_t* __restrict__ o1c, ushort_t* __restrict__ o2a,
    ushort_t* __restrict__ o2b, ushort_t* __restrict__ o2c) {
  int i = blockIdx.x * 256 + threadIdx.x;
  if (i < 49152) {  // 3 x 128x128
    int a = i >> 14, j = i & 16383;
    int nn = j >> 7, k = j & 127;
    const float* s = (a == 0) ? w1a : (a == 1) ? w1b : w1c;
    ushort_t* d = (a == 0) ? o1a : (a == 1) ? o1b : o1c;
    d[j] = f2bf(s[k * 128 + nn]);
  } else if (i < 73728) {  // 3 x 64x128
    int i2 = i - 49152;
    int a = i2 >> 13, j = i2 & 8191;
    int h = j >> 7, k = j & 127;
    const float* s = (a == 0) ? w2a : (a == 1) ? w2b : w2c;
    ushort_t* d = (a == 0) ? o2a : (a == 1) ? o2b : o2c;
    d[j] = f2bf(s[k * 64 + h]);
  }
}

// ---------------- two-level counting sort CSR build ----------------
// vrow in [0, 2n); bucket = vrow >> BKT_BITS (196 buckets of 1024 rows).
// blkhist is BLOCK-MAJOR: blkhist[blk * nb + j].

__global__ __launch_bounds__(256) void coarse_hist(
    const int* __restrict__ rowS, const int* __restrict__ rowF,
    int* __restrict__ bkt_cnt, int* __restrict__ blkhist, int n, int e,
    int nb) {
  __shared__ int lh[200];
  int t = threadIdx.x;
  for (int j = t; j < nb; j += 256) lh[j] = 0;
  __syncthreads();
  long total = 2L * e;
  long stride = (long)NBLK1 * 256;
  for (long i = (long)blockIdx.x * 256 + t; i < total; i += stride) {
    int vrow = (i < e) ? rowS[i] : (n + rowF[i - e]);
    atomicAdd(&lh[vrow >> BKT_BITS], 1);
  }
  __syncthreads();
  int* myrow = blkhist + (long)blockIdx.x * nb;
  for (int j = t; j < nb; j += 256) {
    int h = lh[j];
    myrow[j] = h;  // coalesced
    if (h) atomicAdd(&bkt_cnt[j], h);
  }
}

__global__ __launch_bounds__(256) void coarse_scan(
    const int* __restrict__ cnt, int* __restrict__ off, int nb, int total) {
  __shared__ int lds[256];
  int t = threadIdx.x;
  int c[4];
  int s = 0;
#pragma unroll
  for (int j = 0; j < 4; ++j) {
    int idx = t * 4 + j;
    c[j] = (idx < nb) ? cnt[idx] : 0;
    s += c[j];
  }
  lds[t] = s;
  __syncthreads();
#pragma unroll
  for (int d = 1; d < 256; d <<= 1) {
    int v = (t >= d) ? lds[t - d] : 0;
    __syncthreads();
    lds[t] += v;
    __syncthreads();
  }
  int o = (t == 0) ? 0 : lds[t - 1];
#pragma unroll
  for (int j = 0; j < 4; ++j) {
    int idx = t * 4 + j;
    if (idx < nb) off[idx] = o;
    o += c[j];
  }
  if (t == 0) off[nb] = total;
}

// Per-bucket scan over the NBLK1 per-block counts -> absolute bases.
// grid = nb blocks; block j transforms blkhist[*][j] in place.
__global__ __launch_bounds__(256) void blk_scan(
    int* __restrict__ blkhist, const int* __restrict__ bkt_off, int nb) {
  __shared__ int lds[256];
  int j = blockIdx.x;
  int t = threadIdx.x;
  int h0 = blkhist[(long)(2 * t) * nb + j];
  int h1 = blkhist[(long)(2 * t + 1) * nb + j];
  lds[t] = h0 + h1;
  __syncthreads();
#pragma unroll
  for (int d = 1; d < 256; d <<= 1) {
    int v = (t >= d) ? lds[t - d] : 0;
    __syncthreads();
    lds[t] += v;
    __syncthreads();
  }
  int pre = bkt_off[j] + ((t == 0) ? 0 : lds[t - 1]);
  blkhist[(long)(2 * t) * nb + j] = pre;
  blkhist[(long)(2 * t + 1) * nb + j] = pre + h0;
}

// SINGLE-PASS scatter: bases precomputed in blkhist[blk][j].
// tmp[p] = (col | vlow<<20, val_bits); col < 2^20, vlow = vrow & 1023.
__global__ __launch_bounds__(256) void coarse_scatter(
    const int* __restrict__ rowS, const int* __restrict__ colS,
    const float* __restrict__ valS, const int* __restrict__ rowF,
    const int* __restrict__ colF, const float* __restrict__ valF,
    const int* __restrict__ blkhist, int2* __restrict__ tmp, int n, int e,
    int nb) {
  __shared__ int gb[200];
  __shared__ int lb[200];
  int t = threadIdx.x;
  const int* myrow = blkhist + (long)blockIdx.x * nb;
  for (int j = t; j < nb; j += 256) {
    gb[j] = myrow[j];  // coalesced
    lb[j] = 0;
  }
  __syncthreads();
  long total = 2L * e;
  long stride = (long)NBLK1 * 256;
  for (long i = (long)blockIdx.x * 256 + t; i < total; i += stride) {
    int vrow, c;
    float v;
    if (i < e) {
      vrow = rowS[i];
      c = colS[i];
      v = valS[i];
    } else {
      vrow = n + rowF[i - e];
      c = colF[i - e];
      v = valF[i - e];
    }
    int b = vrow >> BKT_BITS;
    int k = atomicAdd(&lb[b], 1);
    tmp[gb[b] + k] =
        make_int2(c | ((vrow & (BKT_ROWS - 1)) << 20), __float_as_int(v));
  }
}

// one block per 1024-row bucket: LDS hist + scan -> rowptr, then scatter
// within the bucket's ~131KB window (L2-resident).
__global__ __launch_bounds__(256) void fine_sort(
    const int* __restrict__ bkt_off, const int2* __restrict__ tmp,
    int2* __restrict__ packed, int* __restrict__ rowptr, int vtotal,
    int etotal) {
  __shared__ int hist[1024];
  __shared__ int scn[256];
  __shared__ int rowb[1024];
  __shared__ int bump[1024];
  int b = blockIdx.x;
  int t = threadIdx.x;
  int lo = bkt_off[b], hi = bkt_off[b + 1];
#pragma unroll
  for (int j = 0; j < 4; ++j) {
    hist[t + 256 * j] = 0;
    bump[t + 256 * j] = 0;
  }
  __syncthreads();
  for (int i = lo + t; i < hi; i += 256)
    atomicAdd(&hist[((unsigned)tmp[i].x) >> 20], 1);
  __syncthreads();
  int h0 = hist[4 * t], h1 = hist[4 * t + 1], h2 = hist[4 * t + 2],
      h3 = hist[4 * t + 3];
  scn[t] = h0 + h1 + h2 + h3;
  __syncthreads();
#pragma unroll
  for (int d = 1; d < 256; d <<= 1) {
    int v = (t >= d) ? scn[t - d] : 0;
    __syncthreads();
    scn[t] += v;
    __syncthreads();
  }
  int pre = (t == 0) ? 0 : scn[t - 1];
  int r0 = lo + pre;
  int r1 = r0 + h0;
  int r2 = r1 + h1;
  int r3 = r2 + h2;
  rowb[4 * t] = r0;
  rowb[4 * t + 1] = r1;
  rowb[4 * t + 2] = r2;
  rowb[4 * t + 3] = r3;
  int vrow0 = b * BKT_ROWS + 4 * t;
  if (vrow0 < vtotal) rowptr[vrow0] = r0;
  if (vrow0 + 1 < vtotal) rowptr[vrow0 + 1] = r1;
  if (vrow0 + 2 < vtotal) rowptr[vrow0 + 2] = r2;
  if (vrow0 + 3 < vtotal) rowptr[vrow0 + 3] = r3;
  __syncthreads();
  for (int i = lo + t; i < hi; i += 256) {
    int2 p = tmp[i];
    int vl = ((unsigned)p.x) >> 20;
    int dest = rowb[vl] + atomicAdd(&bump[vl], 1);
    packed[dest] = make_int2(p.x & 0xFFFFF, p.y);
  }
  if (b == 0 && t == 0) rowptr[vtotal] = etotal;
}

// ---------------- CSR SpMM (bf16 gather, fp32 accumulate) ----------------

__global__ __launch_bounds__(256) void spmm_csr_128(
    const int* __restrict__ rowptr, const int2* __restrict__ packed,
    const ushort_t* __restrict__ h, ushort_t* __restrict__ Ax, int n) {
  int tid = threadIdx.x;
  int r = blockIdx.x * 8 + (tid >> 5);
  if (r >= n) return;
  int lane = tid & 31;
  int lo = rowptr[r], hi = rowptr[r + 1];
  const ushort4* h4 = (const ushort4*)h;  // row stride = 32 ushort4
  float4 acc = make_float4(0.f, 0.f, 0.f, 0.f);
  int e = lo;
  for (; e + 4 <= hi; e += 4) {
    int2 p0 = packed[e], p1 = packed[e + 1], p2 = packed[e + 2],
         p3 = packed[e + 3];
    float v0 = __int_as_float(p0.y), v1 = __int_as_float(p1.y),
          v2 = __int_as_float(p2.y), v3 = __int_as_float(p3.y);
    ushort4 q0 = h4[(long)p0.x * 32 + lane];
    ushort4 q1 = h4[(long)p1.x * 32 + lane];
    ushort4 q2 = h4[(long)p2.x * 32 + lane];
    ushort4 q3 = h4[(long)p3.x * 32 + lane];
    acc.x += v0 * bf2f(q0.x) + v1 * bf2f(q1.x) + v2 * bf2f(q2.x) + v3 * bf2f(q3.x);
    acc.y += v0 * bf2f(q0.y) + v1 * bf2f(q1.y) + v2 * bf2f(q2.y) + v3 * bf2f(q3.y);
    acc.z += v0 * bf2f(q0.z) + v1 * bf2f(q1.z) + v2 * bf2f(q2.z) + v3 * bf2f(q3.z);
    acc.w += v0 * bf2f(q0.w) + v1 * bf2f(q1.w) + v2 * bf2f(q2.w) + v3 * bf2f(q3.w);
  }
  for (; e < hi; ++e) {
    int2 p = packed[e];
    float v = __int_as_float(p.y);
    ushort4 q = h4[(long)p.x * 32 + lane];
    acc.x += v * bf2f(q.x);
    acc.y += v * bf2f(q.y);
    acc.z += v * bf2f(q.z);
    acc.w += v * bf2f(q.w);
  }
  ushort4 o;
  o.x = f2bf(acc.x);
  o.y = f2bf(acc.y);
  o.z = f2bf(acc.z);
  o.w = f2bf(acc.w);
  ((ushort4*)Ax)[(long)r * 32 + lane] = o;
}

// Dual 64-feat SpMM over INTERLEAVED hI[n][128] (S=0..63, C=64..127):
// one 256B contiguous row gather per edge; lanes 0-15 -> S, 16-31 -> C.
__global__ __launch_bounds__(256) void spmm_dual64(
    const int* __restrict__ rowptr, const int2* __restrict__ packed,
    const ushort_t* __restrict__ hI, const float* __restrict__ bS,
    const float* __restrict__ bC, float* __restrict__ outS,
    float* __restrict__ outC, int n) {
  int tid = threadIdx.x;
  int r = blockIdx.x * 8 + (tid >> 5);
  if (r >= n) return;
  int lane = tid & 31;
  int half = lane >> 4;
  int li = lane & 15;
  const ushort4* h4 = (const ushort4*)hI;  // row = 32 ushort4 (S|C)
  float4 acc = ((const float4*)(half ? bC : bS))[li];
  int lo = rowptr[r], hi = rowptr[r + 1];
  int e = lo;
  for (; e + 4 <= hi; e += 4) {
    int2 p0 = packed[e], p1 = packed[e + 1], p2 = packed[e + 2],
         p3 = packed[e + 3];
    float v0 = __int_as_float(p0.y), v1 = __int_as_float(p1.y),
          v2 = __int_as_float(p2.y), v3 = __int_as_float(p3.y);
    ushort4 q0 = h4[(long)p0.x * 32 + lane];
    ushort4 q1 = h4[(long)p1.x * 32 + lane];
    ushort4 q2 = h4[(long)p2.x * 32 + lane];
    ushort4 q3 = h4[(long)p3.x * 32 + lane];
    acc.x += v0 * bf2f(q0.x) + v1 * bf2f(q1.x) + v2 * bf2f(q2.x) + v3 * bf2f(q3.x);
    acc.y += v0 * bf2f(q0.y) + v1 * bf2f(q1.y) + v2 * bf2f(q2.y) + v3 * bf2f(q3.y);
    acc.z += v0 * bf2f(q0.z) + v1 * bf2f(q1.z) + v2 * bf2f(q2.z) + v3 * bf2f(q3.z);
    acc.w += v0 * bf2f(q0.w) + v1 * bf2f(q1.w) + v2 * bf2f(q2.w) + v3 * bf2f(q3.w);
  }
  for (; e < hi; ++e) {
    int2 p = packed[e];
    float v = __int_as_float(p.y);
    ushort4 q = h4[(long)p.x * 32 + lane];
    acc.x += v * bf2f(q.x);
    acc.y += v * bf2f(q.y);
    acc.z += v * bf2f(q.z);
    acc.w += v * bf2f(q.w);
  }
  float4* o = (float4*)(half ? outC : outS);
  o[(long)r * 16 + li] = acc;
}

// ---------------- fused dense chain, bf16 MFMA, dual weight sets ----------
// Writes into interleaved HI[n][128] at feature offset hoff (0 or 64).
__device__ __forceinline__ void l1l2_chain(
    const ushort_t* __restrict__ Ax, const ushort_t* __restrict__ W1T,
    const float* __restrict__ B1, const ushort_t* __restrict__ W2T,
    ushort_t* __restrict__ HI, int hoff, int n, long node0, int w, int lo16,
    int g, ushort_t (*sp)[136]) {
  // ---- GEMM1 (flipped): S^T = W1T x Ax^T ----
  f32x4 acc1[2][4];
#pragma unroll
  for (int m = 0; m < 2; ++m)
#pragma unroll
    for (int nu = 0; nu < 4; ++nu) acc1[m][nu] = (f32x4){0.f, 0.f, 0.f, 0.f};

#pragma unroll 1
  for (int t = 0; t < 4; ++t) {
    short8 af0 = *(const short8*)(W1T + (32 * w + lo16) * 128 + 32 * t + 8 * g);
    short8 af1 =
        *(const short8*)(W1T + (32 * w + 16 + lo16) * 128 + 32 * t + 8 * g);
#pragma unroll
    for (int nu = 0; nu < 4; ++nu) {
      long node = node0 + 16 * nu + lo16;
      if (node > (long)n - 1) node = (long)n - 1;
      short8 bf = *(const short8*)(Ax + node * 128 + 32 * t + 8 * g);
      acc1[0][nu] =
          __builtin_amdgcn_mfma_f32_16x16x32_bf16(af0, bf, acc1[0][nu], 0, 0, 0);
      acc1[1][nu] =
          __builtin_amdgcn_mfma_f32_16x16x32_bf16(af1, bf, acc1[1][nu], 0, 0, 0);
    }
  }

  // relu + bias, pack 4 contiguous sfeats -> S' LDS
#pragma unroll
  for (int m = 0; m < 2; ++m) {
    int sf = 32 * w + 16 * m + 4 * g;
    float4 b1v = *(const float4*)(B1 + sf);
#pragma unroll
    for (int nu = 0; nu < 4; ++nu) {
      int node_l = 16 * nu + lo16;
      ushort4 pk;
      pk.x = f2bf(fmaxf(acc1[m][nu][0] + b1v.x, 0.f));
      pk.y = f2bf(fmaxf(acc1[m][nu][1] + b1v.y, 0.f));
      pk.z = f2bf(fmaxf(acc1[m][nu][2] + b1v.z, 0.f));
      pk.w = f2bf(fmaxf(acc1[m][nu][3] + b1v.w, 0.f));
      *(ushort4*)(&sp[node_l][sf]) = pk;
    }
  }
  __syncthreads();

  // ---- GEMM2 (standard): H = S' @ W2 ----
  f32x4 acc2[4];
#pragma unroll
  for (int nu = 0; nu < 4; ++nu) acc2[nu] = (f32x4){0.f, 0.f, 0.f, 0.f};
#pragma unroll 1
  for (int t = 0; t < 4; ++t) {
    short8 af = *(const short8*)(&sp[16 * w + lo16][32 * t + 8 * g]);
#pragma unroll
    for (int nu = 0; nu < 4; ++nu) {
      short8 bf =
          *(const short8*)(W2T + (16 * nu + lo16) * 128 + 32 * t + 8 * g);
      acc2[nu] =
          __builtin_amdgcn_mfma_f32_16x16x32_bf16(af, bf, acc2[nu], 0, 0, 0);
    }
  }
#pragma unroll
  for (int nu = 0; nu < 4; ++nu) {
#pragma unroll
    for (int r = 0; r < 4; ++r) {
      long node = node0 + 16 * w + 4 * g + r;
      if (node < n) HI[node * 128 + hoff + 16 * nu + lo16] = f2bf(acc2[nu][r]);
    }
  }
}

__global__ __launch_bounds__(256) void fused_l1l2_mfma_dual(
    const ushort_t* __restrict__ Ax, const ushort_t* __restrict__ W1Ta,
    const float* __restrict__ B1a, const ushort_t* __restrict__ W2Ta,
    const ushort_t* __restrict__ W1Tb, const float* __restrict__ B1b,
    const ushort_t* __restrict__ W2Tb, ushort_t* __restrict__ HI, int n) {
  __shared__ __attribute__((aligned(16))) ushort_t sp[64][136];
  int tid = threadIdx.x;
  int w = tid >> 6;
  int l = tid & 63;
  int lo16 = l & 15;
  int g = l >> 4;
  long node0 = (long)blockIdx.x * 64;

  l1l2_chain(Ax, W1Ta, B1a, W2Ta, HI, 0, n, node0, w, lo16, g, sp);
  __syncthreads();  // WAR on sp before chain B overwrites
  l1l2_chain(Ax, W1Tb, B1b, W2Tb, HI, 64, n, node0, w, lo16, g, sp);
}

// ---------------- final fuse v3 (reduce-scatter; 16 lanes per node) -------
__global__ __launch_bounds__(256) void final_fuse(
    const float* __restrict__ emb1, const float* __restrict__ emb2,
    const float* __restrict__ com1, const float* __restrict__ com2,
    const float* __restrict__ attw1, const float* __restrict__ attb1,
    const float* __restrict__ attw2, const float* __restrict__ mlpw,
    const float* __restrict__ mlpb, float* __restrict__ out_logp,
    float* __restrict__ out_beta, float* __restrict__ out_emb, int n) {
  __shared__ __attribute__((aligned(16))) float w1t[16][64];
  __shared__ __attribute__((aligned(16))) float mwt[8][64];
  __shared__ float b1s[16];
  __shared__ float w2s[16];
  __shared__ float mbs[8];
  int tid = threadIdx.x;
  for (int idx = tid; idx < 1024; idx += 256)
    w1t[idx & 15][idx >> 4] = attw1[idx];
  for (int idx = tid; idx < 512; idx += 256)
    mwt[idx & 7][idx >> 3] = mlpw[idx];
  if (tid < 16) {
    b1s[tid] = attb1[tid];
    w2s[tid] = attw2[tid];
  }
  if (tid < 8) mbs[tid] = mlpb[tid];
  __syncthreads();

  int lane = tid & 15;
  long i = ((long)blockIdx.x * 256 + tid) >> 4;
  bool alive = i < n;
  long ii = alive ? i : (long)(n - 1);

  float4 z0 = ((const float4*)emb1)[ii * 16 + lane];
  float4 z1 = ((const float4*)emb2)[ii * 16 + lane];
  float4 x1 = ((const float4*)com1)[ii * 16 + lane];
  float4 x2 = ((const float4*)com2)[ii * 16 + lane];
  float4 z2 = make_float4(0.5f * (x1.x + x2.x), 0.5f * (x1.y + x2.y),
                          0.5f * (x1.z + x2.z), 0.5f * (x1.w + x2.w));

  // attention partials
  float a0[16], a1[16], a2[16];
#pragma unroll
  for (int m = 0; m < 16; ++m) {
    float4 w = *(const float4*)&w1t[m][lane * 4];
    a0[m] = z0.x * w.x + z0.y * w.y + z0.z * w.z + z0.w * w.w;
    a1[m] = z1.x * w.x + z1.y * w.y + z1.z * w.z + z1.w * w.w;
    a2[m] = z2.x * w.x + z2.y * w.y + z2.z * w.z + z2.w * w.w;
  }
  // reduce-scatter: lane owns unit m = lane
  float A0 = rs16(a0, lane);
  float A1 = rs16(a1, lane);
  float A2 = rs16(a2, lane);
  // per-lane tanh (3 instead of 48), then all-reduce of the 3 scores
  float bm = b1s[lane], wm = w2s[lane];
  float p0 = tanhf(A0 + bm) * wm;
  float p1 = tanhf(A1 + bm) * wm;
  float p2 = tanhf(A2 + bm) * wm;
#pragma unroll
  for (int d = 1; d < 16; d <<= 1) {
    p0 += __shfl_xor(p0, d);
    p1 += __shfl_xor(p1, d);
    p2 += __shfl_xor(p2, d);
  }
  float mx = fmaxf(p0, fmaxf(p1, p2));
  float ex0 = expf(p0 - mx), ex1 = expf(p1 - mx), ex2 = expf(p2 - mx);
  float inv = 1.f / (ex0 + ex1 + ex2);
  float be0 = ex0 * inv, be1 = ex1 * inv, be2 = ex2 * inv;

  float4 em;
  em.x = be0 * z0.x + be1 * z1.x + be2 * z2.x;
  em.y = be0 * z0.y + be1 * z1.y + be2 * z2.y;
  em.z = be0 * z0.z + be1 * z1.z + be2 * z2.z;
  em.w = be0 * z0.w + be1 * z1.w + be2 * z2.w;
  if (alive) ((float4*)out_emb)[i * 16 + lane] = em;

  // logits partials
  float lg[8];
#pragma unroll
  for (int p = 0; p < 8; ++p) {
    float4 w = *(const float4*)&mwt[p][lane * 4];
    lg[p] = em.x * w.x + em.y * w.y + em.z * w.z + em.w * w.w;
  }
  // reduce-scatter 8 elements over 16 lanes; owner index = 4*b8 + 2*b4 + b2,
  // then the bit-0 pair exchange completes the 16-lane sum.
  bool b8 = (lane & 8) != 0;
  float t4[4];
#pragma unroll
  for (int j = 0; j < 4; ++j) {
    float sent = b8 ? lg[j] : lg[j + 4];
    float mine = b8 ? lg[j + 4] : lg[j];
    t4[j] = mine + __shfl_xor(sent, 8);
  }
  bool b4 = (lane & 4) != 0;
  float t2[2];
#pragma unroll
  for (int j = 0; j < 2; ++j) {
    float sent = b4 ? t4[j] : t4[j + 2];
    float mine = b4 ? t4[j + 2] : t4[j];
    t2[j] = mine + __shfl_xor(sent, 4);
  }
  bool b2 = (lane & 2) != 0;
  {
    float sent = b2 ? t2[0] : t2[1];
    float mine = b2 ? t2[1] : t2[0];
    t2[0] = mine + __shfl_xor(sent, 2);
  }
  t2[0] += __shfl_xor(t2[0], 1);  // lanes l, l^1 hold complementary halves
  int myidx = (b8 ? 4 : 0) + (b4 ? 2 : 0) + (b2 ? 1 : 0);
  float lgv = t2[0] + mbs[myidx];
  // all-reduce max & sum over the 8 distinct indices (d = 2,4,8)
  float m2 = lgv;
  m2 = fmaxf(m2, __shfl_xor(m2, 2));
  m2 = fmaxf(m2, __shfl_xor(m2, 4));
  m2 = fmaxf(m2, __shfl_xor(m2, 8));
  float ev = expf(lgv - m2);
  float ssum = ev;
  ssum += __shfl_xor(ssum, 2);
  ssum += __shfl_xor(ssum, 4);
  ssum += __shfl_xor(ssum, 8);
  float ls = m2 + logf(ssum);

  if (alive) {
    if ((lane & 1) == 0) out_logp[i * 8 + myidx] = lgv - ls;
    if (lane == 0) {
      out_beta[i * 3 + 0] = be0;
      out_beta[i * 3 + 1] = be1;
      out_beta[i * 3 + 2] = be2;
    }
  }
}

extern "C" void kernel_launch(void* const* d_in, const int* in_sizes, int n_in,
                              void* d_out, int out_size, void* d_ws,
                              size_t ws_size, hipStream_t stream) {
  const float* x = (const float*)d_in[0];
  const int* srow = (const int*)d_in[1];
  const int* scol_in = (const int*)d_in[2];
  const float* sval_in = (const float*)d_in[3];
  const int* frow = (const int*)d_in[4];
  const int* fcol_in = (const int*)d_in[5];
  const float* fval_in = (const float*)d_in[6];
  const float* w_s1_1 = (const float*)d_in[7];
  const float* b_s1_1 = (const float*)d_in[8];
  const float* w_s1_2 = (const float*)d_in[9];
  const float* b_s1_2 = (const float*)d_in[10];
  const float* w_s2_1 = (const float*)d_in[11];
  const float* b_s2_1 = (const float*)d_in[12];
  const float* w_s2_2 = (const float*)d_in[13];
  const float* b_s2_2 = (const float*)d_in[14];
  const float* w_c_1 = (const float*)d_in[15];
  const float* b_c_1 = (const float*)d_in[16];
  const float* w_c_2 = (const float*)d_in[17];
  const float* b_c_2 = (const float*)d_in[18];
  const float* attw1 = (const float*)d_in[19];
  const float* attb1 = (const float*)d_in[20];
  const float* attw2 = (const float*)d_in[21];
  const float* mlpw = (const float*)d_in[22];
  const float* mlpb = (const float*)d_in[23];

  const int n = in_sizes[0] / 128;  // 100000
  const int e = in_sizes[1];        // 1600000
  const int vtotal = 2 * n;
  const int nb = (vtotal + BKT_ROWS - 1) >> BKT_BITS;  // 196 buckets

  float* out = (float*)d_out;
  float* o_logp = out;
  float* o_beta = out + (size_t)n * 8;
  float* o_emb1 = out + (size_t)n * 11;
  float* o_com1 = o_emb1 + (size_t)n * 64;
  float* o_com2 = o_com1 + (size_t)n * 64;
  float* o_emb2 = o_com2 + (size_t)n * 64;
  float* o_emb = o_emb2 + (size_t)n * 64;

  // x_bf16 in o_emb region (25.6MB, exact fit); overwritten by final_fuse.
  ushort_t* x_bf16 = (ushort_t*)o_emb;
  // tmp (coarse-bucketed edges) in o_emb1 region: consumed by fine_sort
  // before spmm_dual64 writes o_emb1.
  int2* tmp = (int2*)o_emb1;

  // workspace layout (~79MB)
  ushort_t* ax = (ushort_t*)d_ws;                 // n*128 bf16
  ushort_t* hwI = ax + (size_t)n * 128;           // n*128 bf16 (S|C interleaved)
  ushort_t* w1t_s1 = hwI + (size_t)n * 128;       // 128*128 bf16
  ushort_t* w1t_s2 = w1t_s1 + 16384;
  ushort_t* w1t_c = w1t_s2 + 16384;
  ushort_t* w2t_s1 = w1t_c + 16384;               // 64*128 bf16
  ushort_t* w2t_s2 = w2t_s1 + 8192;
  ushort_t* w2t_c = w2t_s2 + 8192;
  int* rowptr = (int*)(w2t_c + 8192);             // 2n+1
  int* bkt_cnt = rowptr + vtotal + 1;             // nb
  int* bkt_off = bkt_cnt + nb;                    // nb+1
  int* blkhist = bkt_off + nb + 1;                // NBLK1*nb (401KB)
  int* tail = blkhist + NBLK1 * nb + 1;           // align to 8B for int2
  int2* packed = (int2*)(tail + ((((size_t)(tail)&7) == 0) ? 0 : 1));

  const int spmmBlocks = (n + 7) / 8;
  const int cvtBlocks = (int)(((long)n * 32 + 255) / 256);
  const int mfmaBlocks = (n + 63) / 64;

  // one-time preprocessing
  cvt_bf16<<<cvtBlocks, 256, 0, stream>>>(x, x_bf16, (long)n * 32);
  prep_weights<<<288, 256, 0, stream>>>(w_s1_1, w_s2_1, w_c_1, w_s1_2, w_s2_2,
                                        w_c_2, w1t_s1, w1t_s2, w1t_c, w2t_s1,
                                        w2t_s2, w2t_c);

  // two-level counting-sort CSR build (both graphs at once)
  hipMemsetAsync(bkt_cnt, 0, (size_t)nb * sizeof(int), stream);
  coarse_hist<<<NBLK1, 256, 0, stream>>>(srow, frow, bkt_cnt, blkhist, n, e,
                                         nb);
  coarse_scan<<<1, 256, 0, stream>>>(bkt_cnt, bkt_off, nb, 2 * e);
  blk_scan<<<nb, 256, 0, stream>>>(blkhist, bkt_off, nb);
  coarse_scatter<<<NBLK1, 256, 0, stream>>>(srow, scol_in, sval_in, frow,
                                            fcol_in, fval_in, blkhist, tmp, n,
                                            e, nb);
  fine_sort<<<nb, 256, 0, stream>>>(bkt_off, tmp, packed, rowptr, vtotal,
                                    2 * e);

  const int* rowptrS = rowptr;      // sadj rows: rowptr[0..n]
  const int* rowptrF = rowptr + n;  // fadj rows: rowptr[n..2n]

  // --- graph sadj: emb1 (w_s1) + com1 (w_c) ---
  spmm_csr_128<<<spmmBlocks, 256, 0, stream>>>(rowptrS, packed, x_bf16, ax, n);
  fused_l1l2_mfma_dual<<<mfmaBlocks, 256, 0, stream>>>(
      ax, w1t_s1, b_s1_1, w2t_s1, w1t_c, b_c_1, w2t_c, hwI, n);
  spmm_dual64<<<spmmBlocks, 256, 0, stream>>>(rowptrS, packed, hwI, b_s1_2,
                                              b_c_2, o_emb1, o_com1, n);

  // --- graph fadj: com2 (w_c) + emb2 (w_s2) ---
  spmm_csr_128<<<spmmBlocks, 256, 0, stream>>>(rowptrF, packed, x_bf16, ax, n);
  fused_l1l2_mfma_dual<<<mfmaBlocks, 256, 0, stream>>>(
      ax, w1t_s2, b_s2_1, w2t_s2, w1t_c, b_c_1, w2t_c, hwI, n);
  spmm_dual64<<<spmmBlocks, 256, 0, stream>>>(rowptrF, packed, hwI, b_s2_2,
                                              b_c_2, o_emb2, o_com2, n);

  final_fuse<<<(int)(((long)n * 16 + 255) / 256), 256, 0, stream>>>(
      o_emb1, o_emb2, o_com1, o_com2, attw1, attb1, attw2, mlpw, mlpb, o_logp,
      o_beta, o_emb, n);
}